// Round 1
// baseline (326.101 us; speedup 1.0000x reference)
//
#include <hip/hip_runtime.h>

typedef float f32x4 __attribute__((ext_vector_type(4)));
typedef __bf16 bf16x8 __attribute__((ext_vector_type(8)));
typedef unsigned short us4 __attribute__((ext_vector_type(4)));

#define DEV __device__ __forceinline__

DEV unsigned short f2bf(float f) {
  union { float f; unsigned int u; } v; v.f = f;
  unsigned int u = v.u;
  return (unsigned short)((u + 0x7FFFu + ((u >> 16) & 1u)) >> 16);
}

typedef const __attribute__((address_space(1))) void* gvp;
typedef __attribute__((address_space(3))) void* lvp;

DEV void gll16(const void* g, void* l) {
  __builtin_amdgcn_global_load_lds((gvp)g, (lvp)l, 16, 0, 0);
}

// ---------------- convert fp32 -> bf16 ----------------
__global__ void k_convert(const float* __restrict__ in, unsigned short* __restrict__ out, int n4) {
  int i = blockIdx.x * blockDim.x + threadIdx.x;
  if (i < n4) {
    float4 v = ((const float4*)in)[i];
    us4 o = { f2bf(v.x), f2bf(v.y), f2bf(v.z), f2bf(v.w) };
    ((us4*)out)[i] = o;
  }
}

// ---------------- transpose 1024x1024 fp32 -> bf16 ----------------
__global__ void k_transpose(const float* __restrict__ in, unsigned short* __restrict__ out) {
  __shared__ float tile[32][33];
  const int bx = blockIdx.x * 32, by = blockIdx.y * 32;
  const int tx = threadIdx.x, ty = threadIdx.y;
#pragma unroll
  for (int r = 0; r < 4; ++r)
    tile[ty + r * 8][tx] = in[(size_t)(by + ty + r * 8) * 1024 + bx + tx];
  __syncthreads();
#pragma unroll
  for (int r = 0; r < 4; ++r)
    out[(size_t)(bx + ty + r * 8) * 1024 + by + tx] = f2bf(tile[tx][ty + r * 8]);
}

// ---------------- generic bf16 GEMM: C[i][j] = sum_k A[i][k]*Bt[j][k] ----------------
// MODE 0: out bf16 in [B,H,S,64] layout, val=(acc+bias[nj])*scale   (q,k proj)
// MODE 1: out bf16 in [B,H,64,S] layout (A rows are weight-n, Bt rows are x-m)  (v^T)
// MODE 2: out fp32 y = acc + bias[nj] + xres[mi*1024+nj]            (out proj + residual)
template<int MODE>
__global__ void k_gemm(const unsigned short* __restrict__ A,
                       const unsigned short* __restrict__ Bt,
                       const float* __restrict__ bias,
                       void* __restrict__ outp,
                       const float* __restrict__ xres,
                       int Kd, float scale) {
  __shared__ unsigned short As[128 * 64];
  __shared__ unsigned short Bs[128 * 64];
  const int tid = threadIdx.x;
  const int lane = tid & 63;
  const int wave = tid >> 6;
  const int l15 = lane & 15;
  const int lq  = lane >> 4;
  const int wm = wave >> 1, wn = wave & 1;
  const int mbase = blockIdx.x * 128;
  const int nbase = blockIdx.y * 128;

  f32x4 acc[4][4] = {};

  for (int kt = 0; kt < Kd; kt += 64) {
    __syncthreads();
#pragma unroll
    for (int c = 0; c < 4; ++c) {
      int e = (c * 256 + tid) * 8;
      int row = e >> 6;
      int o2 = (e * 2) ^ ((row & 7) << 4);
      int col = (o2 >> 1) & 63;
      gll16(A + (size_t)(mbase + row) * Kd + kt + col,
            As + (c * 256 + (tid & ~63)) * 8);
    }
#pragma unroll
    for (int c = 0; c < 4; ++c) {
      int e = (c * 256 + tid) * 8;
      int row = e >> 6;
      int o2 = (e * 2) ^ ((row & 7) << 4);
      int col = (o2 >> 1) & 63;
      gll16(Bt + (size_t)(nbase + row) * Kd + kt + col,
            Bs + (c * 256 + (tid & ~63)) * 8);
    }
    __syncthreads();
#pragma unroll
    for (int ks = 0; ks < 2; ++ks) {
      bf16x8 af[4], bfv[4];
#pragma unroll
      for (int i = 0; i < 4; ++i) {
        int row = wm * 64 + i * 16 + l15;
        int off = row * 128 + ((((ks << 2) | lq) ^ (row & 7)) << 4);
        af[i] = *(const bf16x8*)((const char*)As + off);
      }
#pragma unroll
      for (int j = 0; j < 4; ++j) {
        int row = wn * 64 + j * 16 + l15;
        int off = row * 128 + ((((ks << 2) | lq) ^ (row & 7)) << 4);
        bfv[j] = *(const bf16x8*)((const char*)Bs + off);
      }
#pragma unroll
      for (int i = 0; i < 4; ++i)
#pragma unroll
        for (int j = 0; j < 4; ++j)
          acc[i][j] = __builtin_amdgcn_mfma_f32_16x16x32_bf16(af[i], bfv[j], acc[i][j], 0, 0, 0);
    }
  }

#pragma unroll
  for (int i = 0; i < 4; ++i) {
#pragma unroll
    for (int j = 0; j < 4; ++j) {
#pragma unroll
      for (int r = 0; r < 4; ++r) {
        int mi = mbase + wm * 64 + i * 16 + lq * 4 + r;
        int nj = nbase + wn * 64 + j * 16 + l15;
        float v = acc[i][j][r];
        if constexpr (MODE == 0) {
          v = (v + bias[nj]) * scale;
          int b = mi >> 11, s = mi & 2047, h = nj >> 6, kk = nj & 63;
          ((unsigned short*)outp)[(((size_t)((b << 4) + h) * 2048 + s) << 6) + kk] = f2bf(v);
        } else if constexpr (MODE == 1) {
          v = v + bias[mi];
          int h = mi >> 6, d = mi & 63, b = nj >> 11, s = nj & 2047;
          ((unsigned short*)outp)[(((size_t)((b << 4) + h) << 6) + d) * 2048 + s] = f2bf(v);
        } else {
          size_t idx = (size_t)mi * 1024 + nj;
          ((float*)outp)[idx] = v + bias[nj] + xres[idx];
        }
      }
    }
  }
}

// ---------------- flash attention ----------------
// q,k: [B,H,S,64] bf16 (q pre-scaled by 1/8); vt: [B,H,64,S] bf16; ctx out: [B,S,H,64] bf16
__global__ void k_attn(const unsigned short* __restrict__ q,
                       const unsigned short* __restrict__ k,
                       const unsigned short* __restrict__ vt,
                       unsigned short* __restrict__ ctx) {
  __shared__ unsigned short Qs[64 * 64];
  __shared__ unsigned short Ks[64 * 64];
  __shared__ unsigned short Vt[64 * 64];
  __shared__ unsigned short Ps[64 * 64];

  const int tid = threadIdx.x;
  const int lane = tid & 63;
  const int wave = tid >> 6;
  const int l15 = lane & 15;
  const int lq = lane >> 4;
  const int qbase = blockIdx.x * 64;
  const int bh = blockIdx.y;
  const size_t sl = (size_t)bh << 17;  // bh * S * 64

  // stage Q once (tile is contiguous in global)
#pragma unroll
  for (int c = 0; c < 2; ++c) {
    int e = (c * 256 + tid) * 8;
    int row = e >> 6;
    int o2 = (e * 2) ^ ((row & 7) << 4);
    gll16(q + sl + (size_t)qbase * 64 + (o2 >> 1),
          Qs + (c * 256 + (tid & ~63)) * 8);
  }
  __syncthreads();

  bf16x8 aq[2];
#pragma unroll
  for (int ks = 0; ks < 2; ++ks) {
    int qp = wave * 16 + l15;
    int off = qp * 128 + ((((ks << 2) | lq) ^ (qp & 7)) << 4);
    aq[ks] = *(const bf16x8*)((const char*)Qs + off);
  }

  f32x4 oa[4] = {};
  float mrow[4], lrow[4];
#pragma unroll
  for (int r = 0; r < 4; ++r) { mrow[r] = -1e30f; lrow[r] = 0.f; }

  for (int t = 0; t < 32; ++t) {
    const int kvbase = t * 64;
    __syncthreads();
#pragma unroll
    for (int c = 0; c < 2; ++c) {
      int e = (c * 256 + tid) * 8;
      int row = e >> 6;
      int o2 = (e * 2) ^ ((row & 7) << 4);
      int col = (o2 >> 1) & 63;
      gll16(k + sl + (size_t)kvbase * 64 + (o2 >> 1),
            Ks + (c * 256 + (tid & ~63)) * 8);
      gll16(vt + sl + (size_t)row * 2048 + kvbase + col,
            Vt + (c * 256 + (tid & ~63)) * 8);
    }
    __syncthreads();

    // S = Q K^T  (scale already folded into q)
    f32x4 sc[4] = {};
#pragma unroll
    for (int ks = 0; ks < 2; ++ks) {
#pragma unroll
      for (int nf = 0; nf < 4; ++nf) {
        int row = nf * 16 + l15;
        int off = row * 128 + ((((ks << 2) | lq) ^ (row & 7)) << 4);
        bf16x8 bk = *(const bf16x8*)((const char*)Ks + off);
        sc[nf] = __builtin_amdgcn_mfma_f32_16x16x32_bf16(aq[ks], bk, sc[nf], 0, 0, 0);
      }
    }

    // online softmax (row groups = 16 lanes sharing lq)
    float pr[4][4];
#pragma unroll
    for (int r = 0; r < 4; ++r) {
      float tm = fmaxf(fmaxf(sc[0][r], sc[1][r]), fmaxf(sc[2][r], sc[3][r]));
#pragma unroll
      for (int m = 1; m <= 8; m <<= 1) tm = fmaxf(tm, __shfl_xor(tm, m));
      float mnew = fmaxf(mrow[r], tm);
      float alpha = __expf(mrow[r] - mnew);
      float rs = 0.f;
#pragma unroll
      for (int nf = 0; nf < 4; ++nf) {
        float p = __expf(sc[nf][r] - mnew);
        pr[nf][r] = p;
        rs += p;
      }
#pragma unroll
      for (int m = 1; m <= 8; m <<= 1) rs += __shfl_xor(rs, m);
      lrow[r] = lrow[r] * alpha + rs;
      mrow[r] = mnew;
#pragma unroll
      for (int df = 0; df < 4; ++df) oa[df][r] *= alpha;
    }

    // write P (bf16, swizzled) to wave-private rows of Ps
#pragma unroll
    for (int nf = 0; nf < 4; ++nf)
#pragma unroll
      for (int r = 0; r < 4; ++r) {
        int ql = wave * 16 + lq * 4 + r;
        int kv = nf * 16 + l15;
        int ea = ql * 64 + ((((kv >> 3) ^ (ql & 7)) << 3) | (kv & 7));
        Ps[ea] = f2bf(pr[nf][r]);
      }
    __syncthreads();

    // O += P V
#pragma unroll
    for (int ks = 0; ks < 2; ++ks) {
      int qp = wave * 16 + l15;
      int offp = qp * 128 + ((((ks << 2) | lq) ^ (qp & 7)) << 4);
      bf16x8 ap = *(const bf16x8*)((const char*)Ps + offp);
#pragma unroll
      for (int df = 0; df < 4; ++df) {
        int row = df * 16 + l15;
        int offv = row * 128 + ((((ks << 2) | lq) ^ (row & 7)) << 4);
        bf16x8 bv = *(const bf16x8*)((const char*)Vt + offv);
        oa[df] = __builtin_amdgcn_mfma_f32_16x16x32_bf16(ap, bv, oa[df], 0, 0, 0);
      }
    }
  }

  const int b = bh >> 4, h = bh & 15;
  float inv[4];
#pragma unroll
  for (int r = 0; r < 4; ++r) inv[r] = 1.f / lrow[r];
#pragma unroll
  for (int df = 0; df < 4; ++df)
#pragma unroll
    for (int r = 0; r < 4; ++r) {
      int s = qbase + wave * 16 + lq * 4 + r;
      int d = df * 16 + l15;
      ctx[(size_t)(b * 2048 + s) * 1024 + h * 64 + d] = f2bf(oa[df][r] * inv[r]);
    }
}

// ---------------- LayerNorm over D=1024 ----------------
__global__ void k_ln(const float* __restrict__ y, const float* __restrict__ gamma,
                     const float* __restrict__ beta, float* __restrict__ out) {
  const int row = blockIdx.x;
  const int tid = threadIdx.x;
  const float4 v = ((const float4*)(y + (size_t)row * 1024))[tid];
  float sum = v.x + v.y + v.z + v.w;
  float sq = v.x * v.x + v.y * v.y + v.z * v.z + v.w * v.w;
#pragma unroll
  for (int m = 1; m <= 32; m <<= 1) {
    sum += __shfl_xor(sum, m);
    sq  += __shfl_xor(sq, m);
  }
  __shared__ float s1[4], s2[4];
  const int wv = tid >> 6, lane = tid & 63;
  if (lane == 0) { s1[wv] = sum; s2[wv] = sq; }
  __syncthreads();
  sum = s1[0] + s1[1] + s1[2] + s1[3];
  sq  = s2[0] + s2[1] + s2[2] + s2[3];
  const float mu = sum * (1.f / 1024.f);
  const float rs = rsqrtf(sq * (1.f / 1024.f) - mu * mu + 1e-3f);
  const float4 g  = ((const float4*)gamma)[tid];
  const float4 bb = ((const float4*)beta)[tid];
  float4 o;
  o.x = (v.x - mu) * rs * g.x + bb.x;
  o.y = (v.y - mu) * rs * g.y + bb.y;
  o.z = (v.z - mu) * rs * g.z + bb.z;
  o.w = (v.w - mu) * rs * g.w + bb.w;
  ((float4*)(out + (size_t)row * 1024))[tid] = o;
}

extern "C" void kernel_launch(void* const* d_in, const int* in_sizes, int n_in,
                              void* d_out, int out_size, void* d_ws, size_t ws_size,
                              hipStream_t stream) {
  const float* x  = (const float*)d_in[0];
  const float* Wq = (const float*)d_in[1];
  const float* bq = (const float*)d_in[2];
  const float* Wk = (const float*)d_in[3];
  const float* bk = (const float*)d_in[4];
  const float* Wv = (const float*)d_in[5];
  const float* bv = (const float*)d_in[6];
  const float* Wo = (const float*)d_in[7];
  const float* bo = (const float*)d_in[8];
  const float* gamma = (const float*)d_in[9];
  const float* beta  = (const float*)d_in[10];
  float* out = (float*)d_out;

  char* ws = (char*)d_ws;
  const size_t MB = 1024 * 1024;
  unsigned short* xb  = (unsigned short*)(ws);            // 16MB  x bf16 [8192][1024]
  unsigned short* wqt = (unsigned short*)(ws + 16 * MB);  // 2MB   Wq^T bf16 [1024][1024]
  unsigned short* wkt = (unsigned short*)(ws + 18 * MB);
  unsigned short* wvt = (unsigned short*)(ws + 20 * MB);
  unsigned short* wot = (unsigned short*)(ws + 22 * MB);
  unsigned short* qb  = (unsigned short*)(ws + 24 * MB);  // 16MB  q [B,H,S,64]
  unsigned short* kb  = (unsigned short*)(ws + 40 * MB);  // 16MB  k [B,H,S,64]
  unsigned short* vtb = (unsigned short*)(ws + 56 * MB);  // 16MB  v^T [B,H,64,S]
  unsigned short* ctx = (unsigned short*)(ws + 72 * MB);  // 16MB  ctx [B,S,H,64]
  float* yb = (float*)(ws + 24 * MB);                     // 32MB  y fp32, aliases q/k (dead after attn)

  k_convert<<<8192, 256, 0, stream>>>(x, xb, 2097152);
  dim3 tb(32, 8), tg(32, 32);
  k_transpose<<<tg, tb, 0, stream>>>(Wq, wqt);
  k_transpose<<<tg, tb, 0, stream>>>(Wk, wkt);
  k_transpose<<<tg, tb, 0, stream>>>(Wv, wvt);
  k_transpose<<<tg, tb, 0, stream>>>(Wo, wot);

  // q = (x Wq + bq) * 0.125 ; k = x Wk + bk   -> [B,H,S,64]
  k_gemm<0><<<dim3(64, 8), 256, 0, stream>>>(xb, wqt, bq, qb, nullptr, 1024, 0.125f);
  k_gemm<0><<<dim3(64, 8), 256, 0, stream>>>(xb, wkt, bk, kb, nullptr, 1024, 1.0f);
  // v^T = Wv^T x^T  -> [B,H,64,S]
  k_gemm<1><<<dim3(8, 64), 256, 0, stream>>>(wvt, xb, bv, vtb, nullptr, 1024, 1.0f);

  k_attn<<<dim3(32, 64), 256, 0, stream>>>(qb, kb, vtb, ctx);

  // y = ctx Wo + bo + x  (fp32)
  k_gemm<2><<<dim3(64, 8), 256, 0, stream>>>(ctx, wot, bo, yb, x, 1024, 1.0f);

  k_ln<<<8192, 256, 0, stream>>>(yb, gamma, beta, out);
  (void)in_sizes; (void)n_in; (void)out_size; (void)ws_size;
}

// Round 2
// 262.651 us; speedup vs baseline: 1.2416x; 1.2416x over previous
//
#include <hip/hip_runtime.h>

typedef float f32x4 __attribute__((ext_vector_type(4)));
typedef __bf16 bf16x8 __attribute__((ext_vector_type(8)));
typedef __bf16 bf16x4 __attribute__((ext_vector_type(4)));
typedef unsigned short us4 __attribute__((ext_vector_type(4)));

#define DEV __device__ __forceinline__

DEV unsigned short f2bf(float f) {
  union { float f; unsigned int u; } v; v.f = f;
  unsigned int u = v.u;
  return (unsigned short)((u + 0x7FFFu + ((u >> 16) & 1u)) >> 16);
}

typedef const __attribute__((address_space(1))) void* gvp;
typedef __attribute__((address_space(3))) void* lvp;

DEV void gll16(const void* g, void* l) {
  __builtin_amdgcn_global_load_lds((gvp)g, (lvp)l, 16, 0, 0);
}

// ---------------- convert fp32 -> bf16 ----------------
__global__ void k_convert(const float* __restrict__ in, unsigned short* __restrict__ out, int n4) {
  int i = blockIdx.x * blockDim.x + threadIdx.x;
  if (i < n4) {
    float4 v = ((const float4*)in)[i];
    us4 o = { f2bf(v.x), f2bf(v.y), f2bf(v.z), f2bf(v.w) };
    ((us4*)out)[i] = o;
  }
}

// ---------------- transpose 1024x1024 fp32 -> bf16 ----------------
__global__ void k_transpose(const float* __restrict__ in, unsigned short* __restrict__ out) {
  __shared__ float tile[32][33];
  const int bx = blockIdx.x * 32, by = blockIdx.y * 32;
  const int tx = threadIdx.x, ty = threadIdx.y;
#pragma unroll
  for (int r = 0; r < 4; ++r)
    tile[ty + r * 8][tx] = in[(size_t)(by + ty + r * 8) * 1024 + bx + tx];
  __syncthreads();
#pragma unroll
  for (int r = 0; r < 4; ++r)
    out[(size_t)(bx + ty + r * 8) * 1024 + by + tx] = f2bf(tile[tx][ty + r * 8]);
}

// ---------------- generic bf16 GEMM: C[i][j] = sum_k A[i][k]*Bt[j][k] ----------------
// MODE 0: out bf16 in [B,H,S,64] layout, val=(acc+bias[nj])*scale   (q,k proj)
// MODE 1: out bf16 in [B,H,64,S] layout (A rows are weight-n, Bt rows are x-m)  (v^T)
// MODE 2: out fp32 y = acc + bias[nj] + xres[mi*1024+nj]            (out proj + residual)
template<int MODE>
__global__ void k_gemm(const unsigned short* __restrict__ A,
                       const unsigned short* __restrict__ Bt,
                       const float* __restrict__ bias,
                       void* __restrict__ outp,
                       const float* __restrict__ xres,
                       int Kd, float scale) {
  __shared__ unsigned short As[128 * 64];
  __shared__ unsigned short Bs[128 * 64];
  const int tid = threadIdx.x;
  const int lane = tid & 63;
  const int wave = tid >> 6;
  const int l15 = lane & 15;
  const int lq  = lane >> 4;
  const int wm = wave >> 1, wn = wave & 1;
  const int mbase = blockIdx.x * 128;
  const int nbase = blockIdx.y * 128;

  f32x4 acc[4][4] = {};

  for (int kt = 0; kt < Kd; kt += 64) {
    __syncthreads();
#pragma unroll
    for (int c = 0; c < 4; ++c) {
      int e = (c * 256 + tid) * 8;
      int row = e >> 6;
      int o2 = (e * 2) ^ ((row & 7) << 4);
      int col = (o2 >> 1) & 63;
      gll16(A + (size_t)(mbase + row) * Kd + kt + col,
            As + (c * 256 + (tid & ~63)) * 8);
    }
#pragma unroll
    for (int c = 0; c < 4; ++c) {
      int e = (c * 256 + tid) * 8;
      int row = e >> 6;
      int o2 = (e * 2) ^ ((row & 7) << 4);
      int col = (o2 >> 1) & 63;
      gll16(Bt + (size_t)(nbase + row) * Kd + kt + col,
            Bs + (c * 256 + (tid & ~63)) * 8);
    }
    __syncthreads();
#pragma unroll
    for (int ks = 0; ks < 2; ++ks) {
      bf16x8 af[4], bfv[4];
#pragma unroll
      for (int i = 0; i < 4; ++i) {
        int row = wm * 64 + i * 16 + l15;
        int off = row * 128 + ((((ks << 2) | lq) ^ (row & 7)) << 4);
        af[i] = *(const bf16x8*)((const char*)As + off);
      }
#pragma unroll
      for (int j = 0; j < 4; ++j) {
        int row = wn * 64 + j * 16 + l15;
        int off = row * 128 + ((((ks << 2) | lq) ^ (row & 7)) << 4);
        bfv[j] = *(const bf16x8*)((const char*)Bs + off);
      }
#pragma unroll
      for (int i = 0; i < 4; ++i)
#pragma unroll
        for (int j = 0; j < 4; ++j)
          acc[i][j] = __builtin_amdgcn_mfma_f32_16x16x32_bf16(af[i], bfv[j], acc[i][j], 0, 0, 0);
    }
  }

#pragma unroll
  for (int i = 0; i < 4; ++i) {
#pragma unroll
    for (int j = 0; j < 4; ++j) {
#pragma unroll
      for (int r = 0; r < 4; ++r) {
        int mi = mbase + wm * 64 + i * 16 + lq * 4 + r;
        int nj = nbase + wn * 64 + j * 16 + l15;
        float v = acc[i][j][r];
        if constexpr (MODE == 0) {
          v = (v + bias[nj]) * scale;
          int b = mi >> 11, s = mi & 2047, h = nj >> 6, kk = nj & 63;
          ((unsigned short*)outp)[(((size_t)((b << 4) + h) * 2048 + s) << 6) + kk] = f2bf(v);
        } else if constexpr (MODE == 1) {
          v = v + bias[mi];
          int h = mi >> 6, d = mi & 63, b = nj >> 11, s = nj & 2047;
          ((unsigned short*)outp)[(((size_t)((b << 4) + h) << 6) + d) * 2048 + s] = f2bf(v);
        } else {
          size_t idx = (size_t)mi * 1024 + nj;
          ((float*)outp)[idx] = v + bias[nj] + xres[idx];
        }
      }
    }
  }
}

// ---------------- flash attention (swapped-QK, dbuf, 1 barrier/tile) ----------------
// q,k: [B,H,S,64] bf16 (q pre-scaled by 0.125*log2e); vt: [B,H,64,S] bf16
// ctx out: [B,S,H,64] bf16.  QBLK=128, 4 waves, 2 q-frags/wave, KVBLK=64.
__global__ __launch_bounds__(256, 3) void k_attn(const unsigned short* __restrict__ q,
                       const unsigned short* __restrict__ k,
                       const unsigned short* __restrict__ vt,
                       unsigned short* __restrict__ ctx) {
  __shared__ unsigned short KsB[2][64 * 64];
  __shared__ unsigned short VtB[2][64 * 64];
  __shared__ unsigned short QP[128 * 64];   // Q staged here, then reused as P

  const int tid = threadIdx.x;
  const int lane = tid & 63;
  const int wave = tid >> 6;
  const int l15 = lane & 15;
  const int lq = lane >> 4;

  // XCD swizzle: 1024 blocks -> each XCD owns 128 consecutive swz = 8 full heads
  const int bid = blockIdx.x;
  const int swz = (bid & 7) * 128 + (bid >> 3);
  const int bh = swz >> 4;
  const int qtile = swz & 15;
  const int qbase = qtile * 128;
  const size_t sl = (size_t)bh << 17;   // bh * S * 64

  // ---- prologue: stage Q (128x64) + K0 + V0
#pragma unroll
  for (int c = 0; c < 4; ++c) {
    int e = (c * 256 + tid) * 8;
    int row = e >> 6;
    int o2 = (e * 2) ^ ((row & 7) << 4);
    int col = (o2 >> 1) & 63;
    gll16(q + sl + (size_t)(qbase + row) * 64 + col,
          QP + (c * 256 + (tid & ~63)) * 8);
  }
#pragma unroll
  for (int c = 0; c < 2; ++c) {
    int e = (c * 256 + tid) * 8;
    int row = e >> 6;
    int o2 = (e * 2) ^ ((row & 7) << 4);
    int col = (o2 >> 1) & 63;
    gll16(k + sl + (size_t)row * 64 + col, KsB[0] + (c * 256 + (tid & ~63)) * 8);
    gll16(vt + sl + (size_t)row * 2048 + col, VtB[0] + (c * 256 + (tid & ~63)) * 8);
  }
  __syncthreads();

  bf16x8 aq[2][2];
#pragma unroll
  for (int qf = 0; qf < 2; ++qf)
#pragma unroll
    for (int ks = 0; ks < 2; ++ks) {
      int row = wave * 32 + qf * 16 + l15;
      aq[qf][ks] = *(const bf16x8*)((const char*)QP + row * 128 + ((((ks << 2) | lq) ^ (row & 7)) << 4));
    }

  f32x4 oa[2][4] = {};
  float mrow[2] = { -1e30f, -1e30f };
  float lrow[2] = { 0.f, 0.f };

  int cur = 0;
  for (int t = 0; t < 32; ++t) {
    if (t < 31) {
      const int kvb = (t + 1) * 64;
#pragma unroll
      for (int c = 0; c < 2; ++c) {
        int e = (c * 256 + tid) * 8;
        int row = e >> 6;
        int o2 = (e * 2) ^ ((row & 7) << 4);
        int col = (o2 >> 1) & 63;
        gll16(k + sl + (size_t)(kvb + row) * 64 + col, KsB[cur ^ 1] + (c * 256 + (tid & ~63)) * 8);
        gll16(vt + sl + (size_t)row * 2048 + kvb + col, VtB[cur ^ 1] + (c * 256 + (tid & ~63)) * 8);
      }
    }

    const char* Ksc = (const char*)KsB[cur];
    const char* Vtc = (const char*)VtB[cur];

    // K fragments (shared across both q-frags)
    bf16x8 kf[2][4];
#pragma unroll
    for (int ks = 0; ks < 2; ++ks)
#pragma unroll
      for (int nf = 0; nf < 4; ++nf) {
        int row = nf * 16 + l15;
        kf[ks][nf] = *(const bf16x8*)(Ksc + row * 128 + ((((ks << 2) | lq) ^ (row & 7)) << 4));
      }

#pragma unroll
    for (int qf = 0; qf < 2; ++qf) {
      // S^T = K Q^T : st[nf][r] = S[q=l15][kv = nf*16 + lq*4 + r]   (log2 domain)
      f32x4 st[4] = {};
#pragma unroll
      for (int ks = 0; ks < 2; ++ks)
#pragma unroll
        for (int nf = 0; nf < 4; ++nf)
          st[nf] = __builtin_amdgcn_mfma_f32_16x16x32_bf16(kf[ks][nf], aq[qf][ks], st[nf], 0, 0, 0);

      float tm = st[0][0];
#pragma unroll
      for (int nf = 0; nf < 4; ++nf)
#pragma unroll
        for (int r = 0; r < 4; ++r) tm = fmaxf(tm, st[nf][r]);
      tm = fmaxf(tm, __shfl_xor(tm, 16));
      tm = fmaxf(tm, __shfl_xor(tm, 32));
      float mnew = fmaxf(mrow[qf], tm);
      float alpha = exp2f(mrow[qf] - mnew);
      mrow[qf] = mnew;

      float rs = 0.f;
      float pv_[4][4];
#pragma unroll
      for (int nf = 0; nf < 4; ++nf)
#pragma unroll
        for (int r = 0; r < 4; ++r) {
          float p = exp2f(st[nf][r] - mnew);
          pv_[nf][r] = p;
          rs += p;
        }
      lrow[qf] = lrow[qf] * alpha + rs;   // per-lane partial sum (full sum at epilogue)

      // rescale O by alpha (broadcast per output row)
#pragma unroll
      for (int r = 0; r < 4; ++r) {
        float ar = __shfl(alpha, lq * 4 + r);
#pragma unroll
        for (int df = 0; df < 4; ++df) oa[qf][df][r] *= ar;
      }

      // write P[q][kv] bf16, vectorized b64, wave-private rows, swizzled
      {
        int row = wave * 32 + qf * 16 + l15;
        char* base = (char*)QP + row * 128;
        int sw = (row & 7) << 4;
#pragma unroll
        for (int nf = 0; nf < 4; ++nf) {
          bf16x4 pb = { (__bf16)pv_[nf][0], (__bf16)pv_[nf][1],
                        (__bf16)pv_[nf][2], (__bf16)pv_[nf][3] };
          *(bf16x4*)(base + ((nf * 32 + lq * 8) ^ sw)) = pb;
        }
      }
    }

    // same-wave ds_write -> ds_read ordering (P rows are wave-private, no barrier)
    asm volatile("s_waitcnt lgkmcnt(0)" ::: "memory");

    // O += P V : V fragments shared across q-frags
    bf16x8 bv[2][4];
#pragma unroll
    for (int ks = 0; ks < 2; ++ks)
#pragma unroll
      for (int df = 0; df < 4; ++df) {
        int row = df * 16 + l15;
        bv[ks][df] = *(const bf16x8*)(Vtc + row * 128 + ((((ks << 2) | lq) ^ (row & 7)) << 4));
      }
#pragma unroll
    for (int qf = 0; qf < 2; ++qf) {
      int row = wave * 32 + qf * 16 + l15;
#pragma unroll
      for (int ks = 0; ks < 2; ++ks) {
        bf16x8 ap = *(const bf16x8*)((const char*)QP + row * 128 + ((((ks << 2) | lq) ^ (row & 7)) << 4));
#pragma unroll
        for (int df = 0; df < 4; ++df)
          oa[qf][df] = __builtin_amdgcn_mfma_f32_16x16x32_bf16(ap, bv[ks][df], oa[qf][df], 0, 0, 0);
      }
    }

    __syncthreads();   // next-tile staging complete + all waves done with cur
    cur ^= 1;
  }

  const int b = bh >> 4, h = bh & 15;
#pragma unroll
  for (int qf = 0; qf < 2; ++qf) {
    float lt = lrow[qf];
    lt += __shfl_xor(lt, 16);
    lt += __shfl_xor(lt, 32);
    float inv = 1.f / lt;
#pragma unroll
    for (int r = 0; r < 4; ++r) {
      float ir = __shfl(inv, lq * 4 + r);
      int s = qbase + wave * 32 + qf * 16 + lq * 4 + r;
#pragma unroll
      for (int df = 0; df < 4; ++df) {
        int d = df * 16 + l15;
        ctx[(size_t)(b * 2048 + s) * 1024 + h * 64 + d] = f2bf(oa[qf][df][r] * ir);
      }
    }
  }
}

// ---------------- LayerNorm over D=1024 ----------------
__global__ void k_ln(const float* __restrict__ y, const float* __restrict__ gamma,
                     const float* __restrict__ beta, float* __restrict__ out) {
  const int row = blockIdx.x;
  const int tid = threadIdx.x;
  const float4 v = ((const float4*)(y + (size_t)row * 1024))[tid];
  float sum = v.x + v.y + v.z + v.w;
  float sq = v.x * v.x + v.y * v.y + v.z * v.z + v.w * v.w;
#pragma unroll
  for (int m = 1; m <= 32; m <<= 1) {
    sum += __shfl_xor(sum, m);
    sq  += __shfl_xor(sq, m);
  }
  __shared__ float s1[4], s2[4];
  const int wv = tid >> 6, lane = tid & 63;
  if (lane == 0) { s1[wv] = sum; s2[wv] = sq; }
  __syncthreads();
  sum = s1[0] + s1[1] + s1[2] + s1[3];
  sq  = s2[0] + s2[1] + s2[2] + s2[3];
  const float mu = sum * (1.f / 1024.f);
  const float rs = rsqrtf(sq * (1.f / 1024.f) - mu * mu + 1e-3f);
  const float4 g  = ((const float4*)gamma)[tid];
  const float4 bb = ((const float4*)beta)[tid];
  float4 o;
  o.x = (v.x - mu) * rs * g.x + bb.x;
  o.y = (v.y - mu) * rs * g.y + bb.y;
  o.z = (v.z - mu) * rs * g.z + bb.z;
  o.w = (v.w - mu) * rs * g.w + bb.w;
  ((float4*)(out + (size_t)row * 1024))[tid] = o;
}

extern "C" void kernel_launch(void* const* d_in, const int* in_sizes, int n_in,
                              void* d_out, int out_size, void* d_ws, size_t ws_size,
                              hipStream_t stream) {
  const float* x  = (const float*)d_in[0];
  const float* Wq = (const float*)d_in[1];
  const float* bq = (const float*)d_in[2];
  const float* Wk = (const float*)d_in[3];
  const float* bk = (const float*)d_in[4];
  const float* Wv = (const float*)d_in[5];
  const float* bv = (const float*)d_in[6];
  const float* Wo = (const float*)d_in[7];
  const float* bo = (const float*)d_in[8];
  const float* gamma = (const float*)d_in[9];
  const float* beta  = (const float*)d_in[10];
  float* out = (float*)d_out;

  char* ws = (char*)d_ws;
  const size_t MB = 1024 * 1024;
  unsigned short* xb  = (unsigned short*)(ws);            // 16MB  x bf16 [8192][1024]
  unsigned short* wqt = (unsigned short*)(ws + 16 * MB);  // 2MB   Wq^T bf16
  unsigned short* wkt = (unsigned short*)(ws + 18 * MB);
  unsigned short* wvt = (unsigned short*)(ws + 20 * MB);
  unsigned short* wot = (unsigned short*)(ws + 22 * MB);
  unsigned short* qb  = (unsigned short*)(ws + 24 * MB);  // 16MB  q [B,H,S,64]
  unsigned short* kb  = (unsigned short*)(ws + 40 * MB);  // 16MB  k [B,H,S,64]
  unsigned short* vtb = (unsigned short*)(ws + 56 * MB);  // 16MB  v^T [B,H,64,S]
  unsigned short* ctx = (unsigned short*)(ws + 72 * MB);  // 16MB  ctx [B,S,H,64]
  float* yb = (float*)(ws + 24 * MB);                     // 32MB  y fp32, aliases q/k

  k_convert<<<8192, 256, 0, stream>>>(x, xb, 2097152);
  dim3 tb(32, 8), tg(32, 32);
  k_transpose<<<tg, tb, 0, stream>>>(Wq, wqt);
  k_transpose<<<tg, tb, 0, stream>>>(Wk, wkt);
  k_transpose<<<tg, tb, 0, stream>>>(Wv, wvt);
  k_transpose<<<tg, tb, 0, stream>>>(Wo, wot);

  // q = (x Wq + bq) * 0.125*log2(e)  (exp2-domain softmax); k = x Wk + bk
  k_gemm<0><<<dim3(64, 8), 256, 0, stream>>>(xb, wqt, bq, qb, nullptr, 1024, 0.18033688011112042f);
  k_gemm<0><<<dim3(64, 8), 256, 0, stream>>>(xb, wkt, bk, kb, nullptr, 1024, 1.0f);
  // v^T = Wv^T x^T  -> [B,H,64,S]
  k_gemm<1><<<dim3(8, 64), 256, 0, stream>>>(wvt, xb, bv, vtb, nullptr, 1024, 1.0f);

  k_attn<<<1024, 256, 0, stream>>>(qb, kb, vtb, ctx);

  // y = ctx Wo + bo + x  (fp32)
  k_gemm<2><<<dim3(64, 8), 256, 0, stream>>>(ctx, wot, bo, yb, x, 1024, 1.0f);

  k_ln<<<8192, 256, 0, stream>>>(yb, gamma, beta, out);
  (void)in_sizes; (void)n_in; (void)out_size; (void)ws_size;
}

// Round 3
// 230.904 us; speedup vs baseline: 1.4123x; 1.1375x over previous
//
#include <hip/hip_runtime.h>

typedef float f32x4 __attribute__((ext_vector_type(4)));
typedef __bf16 bf16x8 __attribute__((ext_vector_type(8)));
typedef __bf16 bf16x4 __attribute__((ext_vector_type(4)));
typedef __bf16 bf16x2 __attribute__((ext_vector_type(2)));
typedef unsigned short us4 __attribute__((ext_vector_type(4)));

#define DEV __device__ __forceinline__

DEV unsigned short f2bf(float f) {
  union { float f; unsigned int u; } v; v.f = f;
  unsigned int u = v.u;
  return (unsigned short)((u + 0x7FFFu + ((u >> 16) & 1u)) >> 16);
}

typedef const __attribute__((address_space(1))) void* gvp;
typedef __attribute__((address_space(3))) void* lvp;

DEV void gll16(const void* g, void* l) {
  __builtin_amdgcn_global_load_lds((gvp)g, (lvp)l, 16, 0, 0);
}

DEV float fexp2(float x) { return __builtin_amdgcn_exp2f(x); }

// ---------------- convert fp32 -> bf16 ----------------
__global__ void k_convert(const float* __restrict__ in, unsigned short* __restrict__ out, int n4) {
  int i = blockIdx.x * blockDim.x + threadIdx.x;
  if (i < n4) {
    float4 v = ((const float4*)in)[i];
    us4 o = { f2bf(v.x), f2bf(v.y), f2bf(v.z), f2bf(v.w) };
    ((us4*)out)[i] = o;
  }
}

// ---------------- transpose 1024x1024 fp32 -> bf16 ----------------
__global__ void k_transpose(const float* __restrict__ in, unsigned short* __restrict__ out) {
  __shared__ float tile[32][33];
  const int bx = blockIdx.x * 32, by = blockIdx.y * 32;
  const int tx = threadIdx.x, ty = threadIdx.y;
#pragma unroll
  for (int r = 0; r < 4; ++r)
    tile[ty + r * 8][tx] = in[(size_t)(by + ty + r * 8) * 1024 + bx + tx];
  __syncthreads();
#pragma unroll
  for (int r = 0; r < 4; ++r)
    out[(size_t)(bx + ty + r * 8) * 1024 + by + tx] = f2bf(tile[tx][ty + r * 8]);
}

// ---------------- generic bf16 GEMM: C[i][j] = sum_k A[i][k]*Bt[j][k] ----------------
template<int MODE>
__global__ void k_gemm(const unsigned short* __restrict__ A,
                       const unsigned short* __restrict__ Bt,
                       const float* __restrict__ bias,
                       void* __restrict__ outp,
                       const float* __restrict__ xres,
                       int Kd, float scale) {
  __shared__ unsigned short As[128 * 64];
  __shared__ unsigned short Bs[128 * 64];
  const int tid = threadIdx.x;
  const int lane = tid & 63;
  const int wave = tid >> 6;
  const int l15 = lane & 15;
  const int lq  = lane >> 4;
  const int wm = wave >> 1, wn = wave & 1;
  const int mbase = blockIdx.x * 128;
  const int nbase = blockIdx.y * 128;

  f32x4 acc[4][4] = {};

  for (int kt = 0; kt < Kd; kt += 64) {
    __syncthreads();
#pragma unroll
    for (int c = 0; c < 4; ++c) {
      int e = (c * 256 + tid) * 8;
      int row = e >> 6;
      int o2 = (e * 2) ^ ((row & 7) << 4);
      int col = (o2 >> 1) & 63;
      gll16(A + (size_t)(mbase + row) * Kd + kt + col,
            As + (c * 256 + (tid & ~63)) * 8);
    }
#pragma unroll
    for (int c = 0; c < 4; ++c) {
      int e = (c * 256 + tid) * 8;
      int row = e >> 6;
      int o2 = (e * 2) ^ ((row & 7) << 4);
      int col = (o2 >> 1) & 63;
      gll16(Bt + (size_t)(nbase + row) * Kd + kt + col,
            Bs + (c * 256 + (tid & ~63)) * 8);
    }
    __syncthreads();
#pragma unroll
    for (int ks = 0; ks < 2; ++ks) {
      bf16x8 af[4], bfv[4];
#pragma unroll
      for (int i = 0; i < 4; ++i) {
        int row = wm * 64 + i * 16 + l15;
        int off = row * 128 + ((((ks << 2) | lq) ^ (row & 7)) << 4);
        af[i] = *(const bf16x8*)((const char*)As + off);
      }
#pragma unroll
      for (int j = 0; j < 4; ++j) {
        int row = wn * 64 + j * 16 + l15;
        int off = row * 128 + ((((ks << 2) | lq) ^ (row & 7)) << 4);
        bfv[j] = *(const bf16x8*)((const char*)Bs + off);
      }
#pragma unroll
      for (int i = 0; i < 4; ++i)
#pragma unroll
        for (int j = 0; j < 4; ++j)
          acc[i][j] = __builtin_amdgcn_mfma_f32_16x16x32_bf16(af[i], bfv[j], acc[i][j], 0, 0, 0);
    }
  }

#pragma unroll
  for (int i = 0; i < 4; ++i) {
#pragma unroll
    for (int j = 0; j < 4; ++j) {
#pragma unroll
      for (int r = 0; r < 4; ++r) {
        int mi = mbase + wm * 64 + i * 16 + lq * 4 + r;
        int nj = nbase + wn * 64 + j * 16 + l15;
        float v = acc[i][j][r];
        if constexpr (MODE == 0) {
          v = (v + bias[nj]) * scale;
          int b = mi >> 11, s = mi & 2047, h = nj >> 6, kk = nj & 63;
          ((unsigned short*)outp)[(((size_t)((b << 4) + h) * 2048 + s) << 6) + kk] = f2bf(v);
        } else if constexpr (MODE == 1) {
          v = v + bias[mi];
          int h = mi >> 6, d = mi & 63, b = nj >> 11, s = nj & 2047;
          ((unsigned short*)outp)[(((size_t)((b << 4) + h) << 6) + d) * 2048 + s] = f2bf(v);
        } else {
          size_t idx = (size_t)mi * 1024 + nj;
          ((float*)outp)[idx] = v + bias[nj] + xres[idx];
        }
      }
    }
  }
}

// ---------------- flash attention v3 ----------------
// q,k: [B,H,S,64] bf16 (q pre-scaled by 0.125*log2e); vt: [B,H,64,S] bf16
// ctx out: [B,S,H,64] bf16.  QBLK=128, 4 waves, O^T accumulation (q = l15),
// defer-max, unroll-2 dbuf, 1 barrier/tile.
__global__ __launch_bounds__(256, 3) void k_attn(const unsigned short* __restrict__ q,
                       const unsigned short* __restrict__ k,
                       const unsigned short* __restrict__ vt,
                       unsigned short* __restrict__ ctx) {
  __shared__ unsigned short KsB[2][64 * 64];
  __shared__ unsigned short VtB[2][64 * 64];
  __shared__ unsigned short PT[128 * 64];   // Q staged here, then P, then O^T transpose

  const int tid = threadIdx.x;
  const int lane = tid & 63;
  const int wave = tid >> 6;
  const int l15 = lane & 15;
  const int lq = lane >> 4;

  const int bid = blockIdx.x;
  const int swz = (bid & 7) * 128 + (bid >> 3);
  const int bh = swz >> 4;
  const int qtile = swz & 15;
  const int qbase = qtile * 128;
  const size_t sl = (size_t)bh << 17;

  // ---- prologue: stage Q (128x64) + K0 + V0
#pragma unroll
  for (int c = 0; c < 4; ++c) {
    int e = (c * 256 + tid) * 8;
    int row = e >> 6;
    int o2 = (e * 2) ^ ((row & 7) << 4);
    int col = (o2 >> 1) & 63;
    gll16(q + sl + (size_t)(qbase + row) * 64 + col,
          PT + (c * 256 + (tid & ~63)) * 8);
  }
#pragma unroll
  for (int c = 0; c < 2; ++c) {
    int e = (c * 256 + tid) * 8;
    int row = e >> 6;
    int o2 = (e * 2) ^ ((row & 7) << 4);
    int col = (o2 >> 1) & 63;
    gll16(k + sl + (size_t)row * 64 + col, KsB[0] + (c * 256 + (tid & ~63)) * 8);
    gll16(vt + sl + (size_t)row * 2048 + col, VtB[0] + (c * 256 + (tid & ~63)) * 8);
  }
  __syncthreads();

  // loop-invariant fragment byte offsets
  int fro[2][4];   // K/V frag: row = i*16+l15, slot = (ks*4+lq)^(row&7)
#pragma unroll
  for (int ks = 0; ks < 2; ++ks)
#pragma unroll
    for (int i = 0; i < 4; ++i) {
      int row = i * 16 + l15;
      fro[ks][i] = row * 128 + ((((ks << 2) | lq) ^ (row & 7)) << 4);
    }
  int prow[2], pswz[2], pro[2][2];  // P row base / swizzle / read offsets per qf
#pragma unroll
  for (int qf = 0; qf < 2; ++qf) {
    int row = wave * 32 + qf * 16 + l15;
    prow[qf] = row * 128;
    pswz[qf] = (row & 7) << 4;
#pragma unroll
    for (int ks = 0; ks < 2; ++ks)
      pro[qf][ks] = row * 128 + ((((ks << 2) | lq) ^ (row & 7)) << 4);
  }

  bf16x8 aq[2][2];
#pragma unroll
  for (int qf = 0; qf < 2; ++qf)
#pragma unroll
    for (int ks = 0; ks < 2; ++ks)
      aq[qf][ks] = *(const bf16x8*)((const char*)PT + pro[qf][ks]);

  f32x4 oa[2][4] = {};               // O^T: oa[qf][df][r] = O[d=df*16+lq*4+r][q=l15]
  float mrow[2] = { -1e30f, -1e30f };
  float lrow[2] = { 0.f, 0.f };

#define STAGE_KV(KD, VD, TT) do {                                              \
    const int kvb_ = (TT) * 64;                                                \
    _Pragma("unroll")                                                          \
    for (int c = 0; c < 2; ++c) {                                              \
      int e = (c * 256 + tid) * 8;                                             \
      int row_ = e >> 6;                                                       \
      int o2 = (e * 2) ^ ((row_ & 7) << 4);                                    \
      int col_ = (o2 >> 1) & 63;                                               \
      gll16(k + sl + (size_t)(kvb_ + row_) * 64 + col_,                        \
            (KD) + (c * 256 + (tid & ~63)) * 8);                               \
      gll16(vt + sl + (size_t)row_ * 2048 + kvb_ + col_,                       \
            (VD) + (c * 256 + (tid & ~63)) * 8);                               \
    }                                                                          \
  } while (0)

  auto tile_step = [&](const unsigned short* Ksp, const unsigned short* Vtp) {
    const char* Ksc = (const char*)Ksp;
    const char* Vtc = (const char*)Vtp;
    bf16x8 kf[2][4];
#pragma unroll
    for (int ks = 0; ks < 2; ++ks)
#pragma unroll
      for (int nf = 0; nf < 4; ++nf)
        kf[ks][nf] = *(const bf16x8*)(Ksc + fro[ks][nf]);

#pragma unroll
    for (int qf = 0; qf < 2; ++qf) {
      f32x4 st[4] = {};
      __builtin_amdgcn_s_setprio(1);
#pragma unroll
      for (int ks = 0; ks < 2; ++ks)
#pragma unroll
        for (int nf = 0; nf < 4; ++nf)
          st[nf] = __builtin_amdgcn_mfma_f32_16x16x32_bf16(kf[ks][nf], aq[qf][ks], st[nf], 0, 0, 0);
      __builtin_amdgcn_s_setprio(0);

      float tm = st[0][0];
#pragma unroll
      for (int nf = 0; nf < 4; ++nf)
#pragma unroll
        for (int r = 0; r < 4; ++r) tm = fmaxf(tm, st[nf][r]);
      tm = fmaxf(tm, __shfl_xor(tm, 16));
      tm = fmaxf(tm, __shfl_xor(tm, 32));

      float mcur = mrow[qf];
      if (!__all(tm <= mcur + 10.0f)) {        // defer-max: rescale only on growth
        float mnew = fmaxf(mcur, tm);
        float alpha = fexp2(mcur - mnew);
#pragma unroll
        for (int df = 0; df < 4; ++df) oa[qf][df] *= alpha;
        lrow[qf] *= alpha;
        mrow[qf] = mnew;
        mcur = mnew;
      }

      float rs = 0.f;
      bf16x4 pb[4];
#pragma unroll
      for (int nf = 0; nf < 4; ++nf)
#pragma unroll
        for (int r = 0; r < 4; ++r) {
          float p = fexp2(st[nf][r] - mcur);
          rs += p;
          pb[nf][r] = (__bf16)p;
        }
      lrow[qf] += rs;

      char* base = (char*)PT + prow[qf];
      int sw = pswz[qf];
#pragma unroll
      for (int nf = 0; nf < 4; ++nf)
        *(bf16x4*)(base + ((nf * 32 + lq * 8) ^ sw)) = pb[nf];
    }

    asm volatile("s_waitcnt lgkmcnt(0)" ::: "memory");
    __builtin_amdgcn_sched_barrier(0);

    bf16x8 av[2][4];
#pragma unroll
    for (int ks = 0; ks < 2; ++ks)
#pragma unroll
      for (int df = 0; df < 4; ++df)
        av[ks][df] = *(const bf16x8*)(Vtc + fro[ks][df]);
    __builtin_amdgcn_s_setprio(1);
#pragma unroll
    for (int qf = 0; qf < 2; ++qf)
#pragma unroll
      for (int ks = 0; ks < 2; ++ks) {
        bf16x8 pfr = *(const bf16x8*)((const char*)PT + pro[qf][ks]);
#pragma unroll
        for (int df = 0; df < 4; ++df)
          oa[qf][df] = __builtin_amdgcn_mfma_f32_16x16x32_bf16(av[ks][df], pfr, oa[qf][df], 0, 0, 0);
      }
    __builtin_amdgcn_s_setprio(0);
  };

  for (int t = 0; t < 32; t += 2) {
    STAGE_KV(KsB[1], VtB[1], t + 1);
    tile_step(KsB[0], VtB[0]);
    __syncthreads();
    if (t + 2 < 32) STAGE_KV(KsB[0], VtB[0], t + 2);
    tile_step(KsB[1], VtB[1]);
    __syncthreads();
  }

  // ---- epilogue: normalize, transpose via LDS, coalesced store
#pragma unroll
  for (int qf = 0; qf < 2; ++qf) {
    float lt = lrow[qf];
    lt += __shfl_xor(lt, 16);
    lt += __shfl_xor(lt, 32);
    float inv = 1.f / lt;
    char* base = (char*)PT + prow[qf];
    int sw = pswz[qf];
#pragma unroll
    for (int df = 0; df < 4; ++df)
#pragma unroll
      for (int rp = 0; rp < 2; ++rp) {
        bf16x2 pr2 = { (__bf16)(oa[qf][df][rp * 2] * inv),
                       (__bf16)(oa[qf][df][rp * 2 + 1] * inv) };
        *(bf16x2*)(base + ((df * 32 + lq * 8 + rp * 4) ^ sw)) = pr2;
      }
  }
  __syncthreads();

  const int b = bh >> 4, h = bh & 15;
  {
    int row = tid >> 1, half = tid & 1;
    int sw = (row & 7) << 4;
    unsigned short* gdst = ctx + (size_t)(b * 2048 + qbase + row) * 1024 + h * 64 + half * 32;
#pragma unroll
    for (int i = 0; i < 4; ++i) {
      bf16x8 vv = *(const bf16x8*)((const char*)PT + row * 128 + ((half * 64 + i * 16) ^ sw));
      *(bf16x8*)(gdst + i * 8) = vv;
    }
  }
#undef STAGE_KV
}

// ---------------- LayerNorm over D=1024 ----------------
__global__ void k_ln(const float* __restrict__ y, const float* __restrict__ gamma,
                     const float* __restrict__ beta, float* __restrict__ out) {
  const int row = blockIdx.x;
  const int tid = threadIdx.x;
  const float4 v = ((const float4*)(y + (size_t)row * 1024))[tid];
  float sum = v.x + v.y + v.z + v.w;
  float sq = v.x * v.x + v.y * v.y + v.z * v.z + v.w * v.w;
#pragma unroll
  for (int m = 1; m <= 32; m <<= 1) {
    sum += __shfl_xor(sum, m);
    sq  += __shfl_xor(sq, m);
  }
  __shared__ float s1[4], s2[4];
  const int wv = tid >> 6, lane = tid & 63;
  if (lane == 0) { s1[wv] = sum; s2[wv] = sq; }
  __syncthreads();
  sum = s1[0] + s1[1] + s1[2] + s1[3];
  sq  = s2[0] + s2[1] + s2[2] + s2[3];
  const float mu = sum * (1.f / 1024.f);
  const float rs = rsqrtf(sq * (1.f / 1024.f) - mu * mu + 1e-3f);
  const float4 g  = ((const float4*)gamma)[tid];
  const float4 bb = ((const float4*)beta)[tid];
  float4 o;
  o.x = (v.x - mu) * rs * g.x + bb.x;
  o.y = (v.y - mu) * rs * g.y + bb.y;
  o.z = (v.z - mu) * rs * g.z + bb.z;
  o.w = (v.w - mu) * rs * g.w + bb.w;
  ((float4*)(out + (size_t)row * 1024))[tid] = o;
}

extern "C" void kernel_launch(void* const* d_in, const int* in_sizes, int n_in,
                              void* d_out, int out_size, void* d_ws, size_t ws_size,
                              hipStream_t stream) {
  const float* x  = (const float*)d_in[0];
  const float* Wq = (const float*)d_in[1];
  const float* bq = (const float*)d_in[2];
  const float* Wk = (const float*)d_in[3];
  const float* bk = (const float*)d_in[4];
  const float* Wv = (const float*)d_in[5];
  const float* bv = (const float*)d_in[6];
  const float* Wo = (const float*)d_in[7];
  const float* bo = (const float*)d_in[8];
  const float* gamma = (const float*)d_in[9];
  const float* beta  = (const float*)d_in[10];
  float* out = (float*)d_out;

  char* ws = (char*)d_ws;
  const size_t MB = 1024 * 1024;
  unsigned short* xb  = (unsigned short*)(ws);            // 16MB  x bf16 [8192][1024]
  unsigned short* wqt = (unsigned short*)(ws + 16 * MB);  // 2MB   Wq^T bf16
  unsigned short* wkt = (unsigned short*)(ws + 18 * MB);
  unsigned short* wvt = (unsigned short*)(ws + 20 * MB);
  unsigned short* wot = (unsigned short*)(ws + 22 * MB);
  unsigned short* qb  = (unsigned short*)(ws + 24 * MB);  // 16MB  q [B,H,S,64]
  unsigned short* kb  = (unsigned short*)(ws + 40 * MB);  // 16MB  k [B,H,S,64]
  unsigned short* vtb = (unsigned short*)(ws + 56 * MB);  // 16MB  v^T [B,H,64,S]
  unsigned short* ctx = (unsigned short*)(ws + 72 * MB);  // 16MB  ctx [B,S,H,64]
  float* yb = (float*)(ws + 24 * MB);                     // 32MB  y fp32, aliases q/k

  k_convert<<<8192, 256, 0, stream>>>(x, xb, 2097152);
  dim3 tb(32, 8), tg(32, 32);
  k_transpose<<<tg, tb, 0, stream>>>(Wq, wqt);
  k_transpose<<<tg, tb, 0, stream>>>(Wk, wkt);
  k_transpose<<<tg, tb, 0, stream>>>(Wv, wvt);
  k_transpose<<<tg, tb, 0, stream>>>(Wo, wot);

  // q = (x Wq + bq) * 0.125*log2(e)  (exp2-domain softmax); k = x Wk + bk
  k_gemm<0><<<dim3(64, 8), 256, 0, stream>>>(xb, wqt, bq, qb, nullptr, 1024, 0.18033688011112042f);
  k_gemm<0><<<dim3(64, 8), 256, 0, stream>>>(xb, wkt, bk, kb, nullptr, 1024, 1.0f);
  // v^T = Wv^T x^T  -> [B,H,64,S]
  k_gemm<1><<<dim3(8, 64), 256, 0, stream>>>(wvt, xb, bv, vtb, nullptr, 1024, 1.0f);

  k_attn<<<1024, 256, 0, stream>>>(qb, kb, vtb, ctx);

  // y = ctx Wo + bo + x  (fp32)
  k_gemm<2><<<dim3(64, 8), 256, 0, stream>>>(ctx, wot, bo, yb, x, 1024, 1.0f);

  k_ln<<<8192, 256, 0, stream>>>(yb, gamma, beta, out);
  (void)in_sizes; (void)n_in; (void)out_size; (void)ws_size;
}

// Round 4
// 225.088 us; speedup vs baseline: 1.4488x; 1.0258x over previous
//
#include <hip/hip_runtime.h>

typedef float f32x4 __attribute__((ext_vector_type(4)));
typedef float f32x16 __attribute__((ext_vector_type(16)));
typedef __bf16 bf16x8 __attribute__((ext_vector_type(8)));
typedef __bf16 bf16x4 __attribute__((ext_vector_type(4)));
typedef __bf16 bf16x2 __attribute__((ext_vector_type(2)));
typedef unsigned short us4 __attribute__((ext_vector_type(4)));

#define DEV __device__ __forceinline__

DEV unsigned short f2bf(float f) {
  union { float f; unsigned int u; } v; v.f = f;
  unsigned int u = v.u;
  return (unsigned short)((u + 0x7FFFu + ((u >> 16) & 1u)) >> 16);
}

typedef const __attribute__((address_space(1))) void* gvp;
typedef __attribute__((address_space(3))) void* lvp;

DEV void gll16(const void* g, void* l) {
  __builtin_amdgcn_global_load_lds((gvp)g, (lvp)l, 16, 0, 0);
}

DEV float fexp2(float x) { return __builtin_amdgcn_exp2f(x); }

// ---------------- convert fp32 -> bf16 ----------------
__global__ void k_convert(const float* __restrict__ in, unsigned short* __restrict__ out, int n4) {
  int i = blockIdx.x * blockDim.x + threadIdx.x;
  if (i < n4) {
    float4 v = ((const float4*)in)[i];
    us4 o = { f2bf(v.x), f2bf(v.y), f2bf(v.z), f2bf(v.w) };
    ((us4*)out)[i] = o;
  }
}

// ---------------- transpose 4x 1024x1024 fp32 -> bf16 (z = which weight) ----------------
__global__ void k_transpose4(const float* __restrict__ w0, const float* __restrict__ w1,
                             const float* __restrict__ w2, const float* __restrict__ w3,
                             unsigned short* __restrict__ o0, unsigned short* __restrict__ o1,
                             unsigned short* __restrict__ o2, unsigned short* __restrict__ o3) {
  const float* in = (blockIdx.z == 0) ? w0 : (blockIdx.z == 1) ? w1 : (blockIdx.z == 2) ? w2 : w3;
  unsigned short* out = (blockIdx.z == 0) ? o0 : (blockIdx.z == 1) ? o1 : (blockIdx.z == 2) ? o2 : o3;
  __shared__ float tile[32][33];
  const int bx = blockIdx.x * 32, by = blockIdx.y * 32;
  const int tx = threadIdx.x, ty = threadIdx.y;
#pragma unroll
  for (int r = 0; r < 4; ++r)
    tile[ty + r * 8][tx] = in[(size_t)(by + ty + r * 8) * 1024 + bx + tx];
  __syncthreads();
#pragma unroll
  for (int r = 0; r < 4; ++r)
    out[(size_t)(bx + ty + r * 8) * 1024 + by + tx] = f2bf(tile[tx][ty + r * 8]);
}

// ---------------- generic bf16 GEMM: C[i][j] = sum_k A[i][k]*Bt[j][k] ----------------
template<int MODE>
__global__ void k_gemm(const unsigned short* __restrict__ A,
                       const unsigned short* __restrict__ Bt,
                       const float* __restrict__ bias,
                       void* __restrict__ outp,
                       const float* __restrict__ xres,
                       int Kd, float scale) {
  __shared__ unsigned short As[128 * 64];
  __shared__ unsigned short Bs[128 * 64];
  const int tid = threadIdx.x;
  const int lane = tid & 63;
  const int wave = tid >> 6;
  const int l15 = lane & 15;
  const int lq  = lane >> 4;
  const int wm = wave >> 1, wn = wave & 1;
  const int mbase = blockIdx.x * 128;
  const int nbase = blockIdx.y * 128;

  f32x4 acc[4][4] = {};

  for (int kt = 0; kt < Kd; kt += 64) {
    __syncthreads();
#pragma unroll
    for (int c = 0; c < 4; ++c) {
      int e = (c * 256 + tid) * 8;
      int row = e >> 6;
      int o2 = (e * 2) ^ ((row & 7) << 4);
      int col = (o2 >> 1) & 63;
      gll16(A + (size_t)(mbase + row) * Kd + kt + col,
            As + (c * 256 + (tid & ~63)) * 8);
    }
#pragma unroll
    for (int c = 0; c < 4; ++c) {
      int e = (c * 256 + tid) * 8;
      int row = e >> 6;
      int o2 = (e * 2) ^ ((row & 7) << 4);
      int col = (o2 >> 1) & 63;
      gll16(Bt + (size_t)(nbase + row) * Kd + kt + col,
            Bs + (c * 256 + (tid & ~63)) * 8);
    }
    __syncthreads();
#pragma unroll
    for (int ks = 0; ks < 2; ++ks) {
      bf16x8 af[4], bfv[4];
#pragma unroll
      for (int i = 0; i < 4; ++i) {
        int row = wm * 64 + i * 16 + l15;
        int off = row * 128 + ((((ks << 2) | lq) ^ (row & 7)) << 4);
        af[i] = *(const bf16x8*)((const char*)As + off);
      }
#pragma unroll
      for (int j = 0; j < 4; ++j) {
        int row = wn * 64 + j * 16 + l15;
        int off = row * 128 + ((((ks << 2) | lq) ^ (row & 7)) << 4);
        bfv[j] = *(const bf16x8*)((const char*)Bs + off);
      }
#pragma unroll
      for (int i = 0; i < 4; ++i)
#pragma unroll
        for (int j = 0; j < 4; ++j)
          acc[i][j] = __builtin_amdgcn_mfma_f32_16x16x32_bf16(af[i], bfv[j], acc[i][j], 0, 0, 0);
    }
  }

#pragma unroll
  for (int i = 0; i < 4; ++i) {
#pragma unroll
    for (int j = 0; j < 4; ++j) {
#pragma unroll
      for (int r = 0; r < 4; ++r) {
        int mi = mbase + wm * 64 + i * 16 + lq * 4 + r;
        int nj = nbase + wn * 64 + j * 16 + l15;
        float v = acc[i][j][r];
        if constexpr (MODE == 0) {
          v = (v + bias[nj]) * scale;
          int b = mi >> 11, s = mi & 2047, h = nj >> 6, kk = nj & 63;
          ((unsigned short*)outp)[(((size_t)((b << 4) + h) * 2048 + s) << 6) + kk] = f2bf(v);
        } else if constexpr (MODE == 1) {
          v = v + bias[mi];
          int h = mi >> 6, d = mi & 63, b = nj >> 11, s = nj & 2047;
          ((unsigned short*)outp)[(((size_t)((b << 4) + h) << 6) + d) * 2048 + s] = f2bf(v);
        } else {
          size_t idx = (size_t)mi * 1024 + nj;
          ((float*)outp)[idx] = v + bias[nj] + xres[idx];
        }
      }
    }
  }
}

// ---------------- flash attention v4: 32x32 mfma, P in registers ----------------
// q,k: [B,H,S,64] bf16 (q pre-scaled by 0.125*log2e); vt: [B,H,64,S] bf16
// ctx out: [B,S,H,64] bf16.  QBLK=128, 4 waves (32 q each), KVBLK=64.
__global__ __launch_bounds__(256, 4) void k_attn(const unsigned short* __restrict__ q,
                       const unsigned short* __restrict__ k,
                       const unsigned short* __restrict__ vt,
                       unsigned short* __restrict__ ctx) {
  // KV[buf][0]=K tile [64 kv][64 d], KV[buf][1]=V^T tile [64 d][64 kv]; 32 KB total
  __shared__ unsigned short KV[2][2][64 * 64];

  const int tid = threadIdx.x;
  const int lane = tid & 63;
  const int wave = tid >> 6;
  const int l31 = lane & 31;
  const int l5 = lane >> 5;       // 0 or 1
  const bool lo = (l5 == 0);

  const int bid = blockIdx.x;
  const int swz = (bid & 7) * 128 + (bid >> 3);
  const int bh = swz >> 4;
  const int qtile = swz & 15;
  const int qbase = qtile * 128;
  const size_t sl = (size_t)bh << 17;

  // ---- Q direct to registers: qreg[ds] = Q[qrow][ds*16 + l5*8 + j] (B-operand frags)
  const int qrow = qbase + wave * 32 + l31;
  bf16x8 qreg[4];
#pragma unroll
  for (int ds = 0; ds < 4; ++ds)
    qreg[ds] = *(const bf16x8*)(q + sl + (size_t)qrow * 64 + ds * 16 + l5 * 8);

  // ---- stage K0/V0
#define STAGE_KV(BUF, TT) do {                                                 \
    const int kvb_ = (TT) * 64;                                                \
    _Pragma("unroll")                                                          \
    for (int c = 0; c < 2; ++c) {                                              \
      int e = (c * 256 + tid) * 8;                                             \
      int row_ = e >> 6;                                                       \
      int o2 = (e * 2) ^ ((row_ & 7) << 4);                                    \
      int col_ = (o2 >> 1) & 63;                                               \
      gll16(k + sl + (size_t)(kvb_ + row_) * 64 + col_,                        \
            KV[BUF][0] + (c * 256 + (tid & ~63)) * 8);                         \
      gll16(vt + sl + (size_t)row_ * 2048 + kvb_ + col_,                       \
            KV[BUF][1] + (c * 256 + (tid & ~63)) * 8);                         \
    }                                                                          \
  } while (0)

  STAGE_KV(0, 0);
  __syncthreads();

  f32x16 acc0 = {}, acc1 = {};        // O^T[d = layout + 32*dhalf][q=l31]
  float mrow = -1e30f, lrow = 0.f;

  for (int t = 0; t < 32; ++t) {
    const int cur = t & 1;
    if (t < 31) STAGE_KV(cur ^ 1, t + 1);

    const char* Ksc = (const char*)KV[cur][0];
    const char* Vtc = (const char*)KV[cur][1];

    // ---- QK^T: st[kvh] = S^T[kv = a(reg)+4*l5+32*kvh][q=l31]
    f32x16 st0 = {}, st1 = {};
    __builtin_amdgcn_s_setprio(1);
#pragma unroll
    for (int kvh = 0; kvh < 2; ++kvh) {
      bf16x8 kf[4];
#pragma unroll
      for (int ds = 0; ds < 4; ++ds) {
        int row = kvh * 32 + l31;
        kf[ds] = *(const bf16x8*)(Ksc + row * 128 + (((ds * 32 + l5 * 16)) ^ ((row & 7) << 4)));
      }
      if (kvh == 0) {
#pragma unroll
        for (int ds = 0; ds < 4; ++ds)
          st0 = __builtin_amdgcn_mfma_f32_32x32x16_bf16(kf[ds], qreg[ds], st0, 0, 0, 0);
      } else {
#pragma unroll
        for (int ds = 0; ds < 4; ++ds)
          st1 = __builtin_amdgcn_mfma_f32_32x32x16_bf16(kf[ds], qreg[ds], st1, 0, 0, 0);
      }
    }
    __builtin_amdgcn_s_setprio(0);

    // ---- row max (32 in-lane + 1 swap)
    float tmax[8];
#pragma unroll
    for (int i = 0; i < 8; ++i) tmax[i] = fmaxf(st0[i], st0[i + 8]);
#pragma unroll
    for (int i = 0; i < 8; ++i) tmax[i] = fmaxf(tmax[i], fmaxf(st1[i], st1[i + 8]));
    float tm = fmaxf(fmaxf(fmaxf(tmax[0], tmax[1]), fmaxf(tmax[2], tmax[3])),
                     fmaxf(fmaxf(tmax[4], tmax[5]), fmaxf(tmax[6], tmax[7])));
    tm = fmaxf(tm, __shfl_xor(tm, 32));

    if (!__all(tm <= mrow + 10.0f)) {   // defer-max
      float mnew = fmaxf(mrow, tm);
      float alpha = fexp2(mrow - mnew);
      acc0 *= alpha;
      acc1 *= alpha;
      lrow *= alpha;
      mrow = mnew;
    }
    const float mc = mrow;

    // ---- exp2 + pack to bf16 pairs (pk[kvh][m] = kv pair in a u32)
    unsigned pk0[8], pk1[8];
    float rs0 = 0.f, rs1 = 0.f, rs2 = 0.f, rs3 = 0.f;
#pragma unroll
    for (int m = 0; m < 8; ++m) {
      float a0 = fexp2(st0[2 * m] - mc), a1 = fexp2(st0[2 * m + 1] - mc);
      float b0 = fexp2(st1[2 * m] - mc), b1 = fexp2(st1[2 * m + 1] - mc);
      rs0 += a0; rs1 += a1; rs2 += b0; rs3 += b1;
      union { bf16x2 v; unsigned u; } ua, ub;
      ua.v = bf16x2{ (__bf16)a0, (__bf16)a1 };
      ub.v = bf16x2{ (__bf16)b0, (__bf16)b1 };
      pk0[m] = ua.u; pk1[m] = ub.u;
    }
    lrow += (rs0 + rs1) + (rs2 + rs3);

    // ---- cross-half exchange (lane^32): partner's packs needed for PV B-frags
    // l5=0 sends pk[{2,3,6,7}], l5=1 sends pk[{0,1,4,5}]; recv = what I need.
    unsigned rc0[4], rc1[4];
    {
      const int M0[4] = { 2, 3, 6, 7 };
      const int M1[4] = { 0, 1, 4, 5 };
#pragma unroll
      for (int i = 0; i < 4; ++i) {
        unsigned s0 = lo ? pk0[M0[i]] : pk0[M1[i]];
        unsigned s1 = lo ? pk1[M0[i]] : pk1[M1[i]];
        rc0[i] = (unsigned)__shfl_xor((int)s0, 32);
        rc1[i] = (unsigned)__shfl_xor((int)s1, 32);
      }
    }

    // ---- PV: acc[dhalf] += mfma(V^T-frag, P-frag) over (kvh, kvgl)
#pragma unroll
    for (int kvh = 0; kvh < 2; ++kvh) {
      const unsigned* pk = kvh ? pk1 : pk0;
      const unsigned* rc = kvh ? rc1 : rc0;
#pragma unroll
      for (int kvgl = 0; kvgl < 2; ++kvgl) {
        union { unsigned u[4]; bf16x8 v; } pf;
        pf.u[0] = lo ? pk[4 * kvgl]     : rc[2 * kvgl];
        pf.u[1] = lo ? pk[4 * kvgl + 1] : rc[2 * kvgl + 1];
        pf.u[2] = lo ? rc[2 * kvgl]     : pk[4 * kvgl + 2];
        pf.u[3] = lo ? rc[2 * kvgl + 1] : pk[4 * kvgl + 3];
        const int kvg = 2 * kvh + kvgl;
#pragma unroll
        for (int dh = 0; dh < 2; ++dh) {
          int row = dh * 32 + l31;
          bf16x8 av = *(const bf16x8*)(Vtc + row * 128 + ((kvg * 32 + l5 * 16) ^ ((row & 7) << 4)));
          __builtin_amdgcn_s_setprio(1);
          if (dh == 0) acc0 = __builtin_amdgcn_mfma_f32_32x32x16_bf16(av, pf.v, acc0, 0, 0, 0);
          else         acc1 = __builtin_amdgcn_mfma_f32_32x32x16_bf16(av, pf.v, acc1, 0, 0, 0);
          __builtin_amdgcn_s_setprio(0);
        }
      }
    }

    __syncthreads();
  }

  // ---- epilogue: normalize (lane-local), transpose via LDS, coalesced store
  float lt = lrow + __shfl_xor(lrow, 32);
  float inv = 1.f / lt;

  unsigned short* TR = (unsigned short*)KV;   // 16 KB scratch: [128 q][64 d]
  const int qloc = wave * 32 + l31;
  const int swq = (qloc & 7) << 4;
#pragma unroll
  for (int dh = 0; dh < 2; ++dh) {
    const f32x16& ac = dh ? acc1 : acc0;
#pragma unroll
    for (int g3 = 0; g3 < 4; ++g3) {
      bf16x4 o4 = { (__bf16)(ac[4 * g3] * inv), (__bf16)(ac[4 * g3 + 1] * inv),
                    (__bf16)(ac[4 * g3 + 2] * inv), (__bf16)(ac[4 * g3 + 3] * inv) };
      *(bf16x4*)((char*)TR + qloc * 128 + ((dh * 64 + g3 * 16 + l5 * 8) ^ swq)) = o4;
    }
  }
  __syncthreads();

  const int b = bh >> 4, h = bh & 15;
  {
    int row = tid >> 1, half = tid & 1;
    int sw = (row & 7) << 4;
    unsigned short* gdst = ctx + (size_t)(b * 2048 + qbase + row) * 1024 + h * 64 + half * 32;
#pragma unroll
    for (int i = 0; i < 4; ++i) {
      bf16x8 vv = *(const bf16x8*)((const char*)TR + row * 128 + ((half * 64 + i * 16) ^ sw));
      *(bf16x8*)(gdst + i * 8) = vv;
    }
  }
#undef STAGE_KV
}

// ---------------- LayerNorm over D=1024 ----------------
__global__ void k_ln(const float* __restrict__ y, const float* __restrict__ gamma,
                     const float* __restrict__ beta, float* __restrict__ out) {
  const int row = blockIdx.x;
  const int tid = threadIdx.x;
  const float4 v = ((const float4*)(y + (size_t)row * 1024))[tid];
  float sum = v.x + v.y + v.z + v.w;
  float sq = v.x * v.x + v.y * v.y + v.z * v.z + v.w * v.w;
#pragma unroll
  for (int m = 1; m <= 32; m <<= 1) {
    sum += __shfl_xor(sum, m);
    sq  += __shfl_xor(sq, m);
  }
  __shared__ float s1[4], s2[4];
  const int wv = tid >> 6, lane = tid & 63;
  if (lane == 0) { s1[wv] = sum; s2[wv] = sq; }
  __syncthreads();
  sum = s1[0] + s1[1] + s1[2] + s1[3];
  sq  = s2[0] + s2[1] + s2[2] + s2[3];
  const float mu = sum * (1.f / 1024.f);
  const float rs = rsqrtf(sq * (1.f / 1024.f) - mu * mu + 1e-3f);
  const float4 g  = ((const float4*)gamma)[tid];
  const float4 bb = ((const float4*)beta)[tid];
  float4 o;
  o.x = (v.x - mu) * rs * g.x + bb.x;
  o.y = (v.y - mu) * rs * g.y + bb.y;
  o.z = (v.z - mu) * rs * g.z + bb.z;
  o.w = (v.w - mu) * rs * g.w + bb.w;
  ((float4*)(out + (size_t)row * 1024))[tid] = o;
}

extern "C" void kernel_launch(void* const* d_in, const int* in_sizes, int n_in,
                              void* d_out, int out_size, void* d_ws, size_t ws_size,
                              hipStream_t stream) {
  const float* x  = (const float*)d_in[0];
  const float* Wq = (const float*)d_in[1];
  const float* bq = (const float*)d_in[2];
  const float* Wk = (const float*)d_in[3];
  const float* bk = (const float*)d_in[4];
  const float* Wv = (const float*)d_in[5];
  const float* bv = (const float*)d_in[6];
  const float* Wo = (const float*)d_in[7];
  const float* bo = (const float*)d_in[8];
  const float* gamma = (const float*)d_in[9];
  const float* beta  = (const float*)d_in[10];
  float* out = (float*)d_out;

  char* ws = (char*)d_ws;
  const size_t MB = 1024 * 1024;
  unsigned short* xb  = (unsigned short*)(ws);            // 16MB  x bf16 [8192][1024]
  unsigned short* wqt = (unsigned short*)(ws + 16 * MB);  // 2MB   Wq^T bf16
  unsigned short* wkt = (unsigned short*)(ws + 18 * MB);
  unsigned short* wvt = (unsigned short*)(ws + 20 * MB);
  unsigned short* wot = (unsigned short*)(ws + 22 * MB);
  unsigned short* qb  = (unsigned short*)(ws + 24 * MB);  // 16MB  q [B,H,S,64]
  unsigned short* kb  = (unsigned short*)(ws + 40 * MB);  // 16MB  k [B,H,S,64]
  unsigned short* vtb = (unsigned short*)(ws + 56 * MB);  // 16MB  v^T [B,H,64,S]
  unsigned short* ctx = (unsigned short*)(ws + 72 * MB);  // 16MB  ctx [B,S,H,64]
  float* yb = (float*)(ws + 24 * MB);                     // 32MB  y fp32, aliases q/k

  k_convert<<<8192, 256, 0, stream>>>(x, xb, 2097152);
  dim3 tb(32, 8), tg(32, 32, 4);
  k_transpose4<<<tg, tb, 0, stream>>>(Wq, Wk, Wv, Wo, wqt, wkt, wvt, wot);

  // q = (x Wq + bq) * 0.125*log2(e)  (exp2-domain softmax); k = x Wk + bk
  k_gemm<0><<<dim3(64, 8), 256, 0, stream>>>(xb, wqt, bq, qb, nullptr, 1024, 0.18033688011112042f);
  k_gemm<0><<<dim3(64, 8), 256, 0, stream>>>(xb, wkt, bk, kb, nullptr, 1024, 1.0f);
  // v^T = Wv^T x^T  -> [B,H,64,S]
  k_gemm<1><<<dim3(8, 64), 256, 0, stream>>>(wvt, xb, bv, vtb, nullptr, 1024, 1.0f);

  k_attn<<<1024, 256, 0, stream>>>(qb, kb, vtb, ctx);

  // y = ctx Wo + bo + x  (fp32)
  k_gemm<2><<<dim3(64, 8), 256, 0, stream>>>(ctx, wot, bo, yb, x, 1024, 1.0f);

  k_ln<<<8192, 256, 0, stream>>>(yb, gamma, beta, out);
  (void)in_sizes; (void)n_in; (void)out_size; (void)ws_size;
}

// Round 5
// 207.978 us; speedup vs baseline: 1.5680x; 1.0823x over previous
//
#include <hip/hip_runtime.h>

typedef float f32x4 __attribute__((ext_vector_type(4)));
typedef float f32x16 __attribute__((ext_vector_type(16)));
typedef __bf16 bf16x8 __attribute__((ext_vector_type(8)));
typedef __bf16 bf16x4 __attribute__((ext_vector_type(4)));
typedef __bf16 bf16x2 __attribute__((ext_vector_type(2)));
typedef unsigned short us4 __attribute__((ext_vector_type(4)));

#define DEV __device__ __forceinline__

DEV unsigned short f2bf(float f) {
  union { float f; unsigned int u; } v; v.f = f;
  unsigned int u = v.u;
  return (unsigned short)((u + 0x7FFFu + ((u >> 16) & 1u)) >> 16);
}

typedef const __attribute__((address_space(1))) void* gvp;
typedef __attribute__((address_space(3))) void* lvp;

DEV void gll16(const void* g, void* l) {
  __builtin_amdgcn_global_load_lds((gvp)g, (lvp)l, 16, 0, 0);
}

DEV float fexp2(float x) { return __builtin_amdgcn_exp2f(x); }

// v_permlane32_swap_b32 a, b:  a' = {a_lo, b_lo}, b' = {a_hi, b_hi}
// (a' hi-lanes receive b from the lo partner; b' lo-lanes receive a from the hi partner)
DEV void plswap(unsigned& a, unsigned& b) {
  asm("v_permlane32_swap_b32 %0, %1" : "+v"(a), "+v"(b));
}
DEV float xhalf_max(float v) {
  union { float f; unsigned u; } a, b;
  a.f = v; b.f = v;
  plswap(a.u, b.u);
  return fmaxf(a.f, b.f);
}
DEV float xhalf_sum(float v) {
  union { float f; unsigned u; } a, b;
  a.f = v; b.f = v;
  plswap(a.u, b.u);
  return a.f + b.f;
}

// ---------------- convert fp32 -> bf16 ----------------
__global__ void k_convert(const float* __restrict__ in, unsigned short* __restrict__ out, int n4) {
  int i = blockIdx.x * blockDim.x + threadIdx.x;
  if (i < n4) {
    float4 v = ((const float4*)in)[i];
    us4 o = { f2bf(v.x), f2bf(v.y), f2bf(v.z), f2bf(v.w) };
    ((us4*)out)[i] = o;
  }
}

// ---------------- transpose 4x 1024x1024 fp32 -> bf16 (z = which weight) ----------------
__global__ void k_transpose4(const float* __restrict__ w0, const float* __restrict__ w1,
                             const float* __restrict__ w2, const float* __restrict__ w3,
                             unsigned short* __restrict__ o0, unsigned short* __restrict__ o1,
                             unsigned short* __restrict__ o2, unsigned short* __restrict__ o3) {
  const float* in = (blockIdx.z == 0) ? w0 : (blockIdx.z == 1) ? w1 : (blockIdx.z == 2) ? w2 : w3;
  unsigned short* out = (blockIdx.z == 0) ? o0 : (blockIdx.z == 1) ? o1 : (blockIdx.z == 2) ? o2 : o3;
  __shared__ float tile[32][33];
  const int bx = blockIdx.x * 32, by = blockIdx.y * 32;
  const int tx = threadIdx.x, ty = threadIdx.y;
#pragma unroll
  for (int r = 0; r < 4; ++r)
    tile[ty + r * 8][tx] = in[(size_t)(by + ty + r * 8) * 1024 + bx + tx];
  __syncthreads();
#pragma unroll
  for (int r = 0; r < 4; ++r)
    out[(size_t)(bx + ty + r * 8) * 1024 + by + tx] = f2bf(tile[tx][ty + r * 8]);
}

// ---------------- generic bf16 GEMM: C[i][j] = sum_k A[i][k]*Bt[j][k] ----------------
template<int MODE>
__global__ void k_gemm(const unsigned short* __restrict__ A,
                       const unsigned short* __restrict__ Bt,
                       const float* __restrict__ bias,
                       void* __restrict__ outp,
                       const float* __restrict__ xres,
                       int Kd, float scale) {
  __shared__ unsigned short As[128 * 64];
  __shared__ unsigned short Bs[128 * 64];
  const int tid = threadIdx.x;
  const int lane = tid & 63;
  const int wave = tid >> 6;
  const int l15 = lane & 15;
  const int lq  = lane >> 4;
  const int wm = wave >> 1, wn = wave & 1;
  const int mbase = blockIdx.x * 128;
  const int nbase = blockIdx.y * 128;

  f32x4 acc[4][4] = {};

  for (int kt = 0; kt < Kd; kt += 64) {
    __syncthreads();
#pragma unroll
    for (int c = 0; c < 4; ++c) {
      int e = (c * 256 + tid) * 8;
      int row = e >> 6;
      int o2 = (e * 2) ^ ((row & 7) << 4);
      int col = (o2 >> 1) & 63;
      gll16(A + (size_t)(mbase + row) * Kd + kt + col,
            As + (c * 256 + (tid & ~63)) * 8);
    }
#pragma unroll
    for (int c = 0; c < 4; ++c) {
      int e = (c * 256 + tid) * 8;
      int row = e >> 6;
      int o2 = (e * 2) ^ ((row & 7) << 4);
      int col = (o2 >> 1) & 63;
      gll16(Bt + (size_t)(nbase + row) * Kd + kt + col,
            Bs + (c * 256 + (tid & ~63)) * 8);
    }
    __syncthreads();
#pragma unroll
    for (int ks = 0; ks < 2; ++ks) {
      bf16x8 af[4], bfv[4];
#pragma unroll
      for (int i = 0; i < 4; ++i) {
        int row = wm * 64 + i * 16 + l15;
        int off = row * 128 + ((((ks << 2) | lq) ^ (row & 7)) << 4);
        af[i] = *(const bf16x8*)((const char*)As + off);
      }
#pragma unroll
      for (int j = 0; j < 4; ++j) {
        int row = wn * 64 + j * 16 + l15;
        int off = row * 128 + ((((ks << 2) | lq) ^ (row & 7)) << 4);
        bfv[j] = *(const bf16x8*)((const char*)Bs + off);
      }
#pragma unroll
      for (int i = 0; i < 4; ++i)
#pragma unroll
        for (int j = 0; j < 4; ++j)
          acc[i][j] = __builtin_amdgcn_mfma_f32_16x16x32_bf16(af[i], bfv[j], acc[i][j], 0, 0, 0);
    }
  }

#pragma unroll
  for (int i = 0; i < 4; ++i) {
#pragma unroll
    for (int j = 0; j < 4; ++j) {
#pragma unroll
      for (int r = 0; r < 4; ++r) {
        int mi = mbase + wm * 64 + i * 16 + lq * 4 + r;
        int nj = nbase + wn * 64 + j * 16 + l15;
        float v = acc[i][j][r];
        if constexpr (MODE == 0) {
          v = (v + bias[nj]) * scale;
          int b = mi >> 11, s = mi & 2047, h = nj >> 6, kk = nj & 63;
          ((unsigned short*)outp)[(((size_t)((b << 4) + h) * 2048 + s) << 6) + kk] = f2bf(v);
        } else if constexpr (MODE == 1) {
          v = v + bias[mi];
          int h = mi >> 6, d = mi & 63, b = nj >> 11, s = nj & 2047;
          ((unsigned short*)outp)[(((size_t)((b << 4) + h) << 6) + d) * 2048 + s] = f2bf(v);
        } else {
          size_t idx = (size_t)mi * 1024 + nj;
          ((float*)outp)[idx] = v + bias[nj] + xres[idx];
        }
      }
    }
  }
}

// ---------------- flash attention v5: 32x32 mfma, P in regs, permlane exchange ----------------
// q,k: [B,H,S,64] bf16 (q pre-scaled by 0.125*log2e); vt: [B,H,64,S] bf16
// ctx out: [B,S,H,64] bf16.  QBLK=128, 4 waves (32 q each), KVBLK=64.
__global__ __launch_bounds__(256, 4) void k_attn(const unsigned short* __restrict__ q,
                       const unsigned short* __restrict__ k,
                       const unsigned short* __restrict__ vt,
                       unsigned short* __restrict__ ctx) {
  // KV[buf][0]=K tile [64 kv][64 d], KV[buf][1]=V^T tile [64 d][64 kv]; 32 KB total
  __shared__ unsigned short KV[2][2][64 * 64];

  const int tid = threadIdx.x;
  const int lane = tid & 63;
  const int wave = tid >> 6;
  const int l31 = lane & 31;
  const int l5 = lane >> 5;       // 0 or 1

  const int bid = blockIdx.x;
  const int swz = (bid & 7) * 128 + (bid >> 3);
  const int bh = swz >> 4;
  const int qtile = swz & 15;
  const int qbase = qtile * 128;
  const size_t sl = (size_t)bh << 17;

  // ---- Q direct to registers: qreg[ds] = Q[qrow][ds*16 + l5*8 + j] (B-operand frags)
  const int qrow = qbase + wave * 32 + l31;
  bf16x8 qreg[4];
#pragma unroll
  for (int ds = 0; ds < 4; ++ds)
    qreg[ds] = *(const bf16x8*)(q + sl + (size_t)qrow * 64 + ds * 16 + l5 * 8);

#define STAGE_KV(BUF, TT) do {                                                 \
    const int kvb_ = (TT) * 64;                                                \
    _Pragma("unroll")                                                          \
    for (int c = 0; c < 2; ++c) {                                              \
      int e = (c * 256 + tid) * 8;                                             \
      int row_ = e >> 6;                                                       \
      int o2 = (e * 2) ^ ((row_ & 7) << 4);                                    \
      int col_ = (o2 >> 1) & 63;                                               \
      gll16(k + sl + (size_t)(kvb_ + row_) * 64 + col_,                        \
            KV[BUF][0] + (c * 256 + (tid & ~63)) * 8);                         \
      gll16(vt + sl + (size_t)row_ * 2048 + kvb_ + col_,                       \
            KV[BUF][1] + (c * 256 + (tid & ~63)) * 8);                         \
    }                                                                          \
  } while (0)

  STAGE_KV(0, 0);
  __syncthreads();

  f32x16 acc0 = {}, acc1 = {};        // O^T[d = layout + 32*dhalf][q=l31]
  float mrow = -1e30f, lrow = 0.f;

  for (int t = 0; t < 32; ++t) {
    const int cur = t & 1;
    if (t < 31) STAGE_KV(cur ^ 1, t + 1);

    const char* Ksc = (const char*)KV[cur][0];
    const char* Vtc = (const char*)KV[cur][1];

    // ---- QK^T: st = S^T[kv][q=l31], kv per 32x32 C-layout
    f32x16 st0 = {}, st1 = {};
    __builtin_amdgcn_s_setprio(1);
#pragma unroll
    for (int kvh = 0; kvh < 2; ++kvh) {
      bf16x8 kf[4];
#pragma unroll
      for (int ds = 0; ds < 4; ++ds) {
        int row = kvh * 32 + l31;
        kf[ds] = *(const bf16x8*)(Ksc + row * 128 + (((ds * 32 + l5 * 16)) ^ ((row & 7) << 4)));
      }
      if (kvh == 0) {
#pragma unroll
        for (int ds = 0; ds < 4; ++ds)
          st0 = __builtin_amdgcn_mfma_f32_32x32x16_bf16(kf[ds], qreg[ds], st0, 0, 0, 0);
      } else {
#pragma unroll
        for (int ds = 0; ds < 4; ++ds)
          st1 = __builtin_amdgcn_mfma_f32_32x32x16_bf16(kf[ds], qreg[ds], st1, 0, 0, 0);
      }
    }
    __builtin_amdgcn_s_setprio(0);

    // ---- row max: 31 in-lane (max3-friendly) + 1 permlane swap
    float tmax[8];
#pragma unroll
    for (int i = 0; i < 8; ++i) tmax[i] = fmaxf(st0[i], st0[i + 8]);
#pragma unroll
    for (int i = 0; i < 8; ++i) tmax[i] = fmaxf(tmax[i], fmaxf(st1[i], st1[i + 8]));
    float tm = fmaxf(fmaxf(fmaxf(tmax[0], tmax[1]), fmaxf(tmax[2], tmax[3])),
                     fmaxf(fmaxf(tmax[4], tmax[5]), fmaxf(tmax[6], tmax[7])));
    tm = xhalf_max(tm);

    if (!__all(tm <= mrow + 10.0f)) {   // defer-max
      float mnew = fmaxf(mrow, tm);
      float alpha = fexp2(mrow - mnew);
      acc0 *= alpha;
      acc1 *= alpha;
      lrow *= alpha;
      mrow = mnew;
    }
    const float mc = mrow;

    // ---- exp2 + pack to bf16 pairs (pk[kvh][m] = kv pair in a u32)
    unsigned pk0[8], pk1[8];
    float rs0 = 0.f, rs1 = 0.f, rs2 = 0.f, rs3 = 0.f;
#pragma unroll
    for (int m = 0; m < 8; ++m) {
      float a0 = fexp2(st0[2 * m] - mc), a1 = fexp2(st0[2 * m + 1] - mc);
      float b0 = fexp2(st1[2 * m] - mc), b1 = fexp2(st1[2 * m + 1] - mc);
      rs0 += a0; rs1 += a1; rs2 += b0; rs3 += b1;
      union { bf16x2 v; unsigned u; } ua, ub;
      ua.v = bf16x2{ (__bf16)a0, (__bf16)a1 };
      ub.v = bf16x2{ (__bf16)b0, (__bf16)b1 };
      pk0[m] = ua.u; pk1[m] = ub.u;
    }
    lrow += (rs0 + rs1) + (rs2 + rs3);

    // ---- V^T fragments (issue ds_reads; latency hides under permlane/VALU below)
    bf16x8 av[2][4];
#pragma unroll
    for (int kvg = 0; kvg < 4; ++kvg)
#pragma unroll
      for (int dh = 0; dh < 2; ++dh) {
        int row = dh * 32 + l31;
        av[dh][kvg] = *(const bf16x8*)(Vtc + row * 128 + ((kvg * 32 + l5 * 16) ^ ((row & 7) << 4)));
      }

    // ---- PV B-fragments via permlane32_swap:
    // swap(pk[4g+j], pk[4g+2+j]) -> u[j] = {lo: own pk[4g+j], hi: partner pk[4g+2+j]},
    //                               u[2+j] = {lo: partner pk[4g+j], hi: own pk[4g+2+j]}
    union PF { unsigned u[4]; bf16x8 v; };
    PF pf[2][2];
#pragma unroll
    for (int kvh = 0; kvh < 2; ++kvh) {
      unsigned* pk = kvh ? pk1 : pk0;
#pragma unroll
      for (int g = 0; g < 2; ++g)
#pragma unroll
        for (int j = 0; j < 2; ++j) {
          unsigned a = pk[4 * g + j], b = pk[4 * g + 2 + j];
          plswap(a, b);
          pf[kvh][g].u[j] = a;
          pf[kvh][g].u[2 + j] = b;
        }
    }

    // ---- PV: acc[dh] += mfma(V^T-frag, P-frag) over kvg = 2*kvh + g
    __builtin_amdgcn_s_setprio(1);
#pragma unroll
    for (int kvh = 0; kvh < 2; ++kvh)
#pragma unroll
      for (int g = 0; g < 2; ++g) {
        const int kvg = 2 * kvh + g;
        acc0 = __builtin_amdgcn_mfma_f32_32x32x16_bf16(av[0][kvg], pf[kvh][g].v, acc0, 0, 0, 0);
        acc1 = __builtin_amdgcn_mfma_f32_32x32x16_bf16(av[1][kvg], pf[kvh][g].v, acc1, 0, 0, 0);
      }
    __builtin_amdgcn_s_setprio(0);

    __syncthreads();
  }

  // ---- epilogue: normalize (lane-local), transpose via LDS, coalesced store
  float inv = 1.f / xhalf_sum(lrow);

  unsigned short* TR = (unsigned short*)KV;   // 16 KB scratch: [128 q][64 d]
  const int qloc = wave * 32 + l31;
  const int swq = (qloc & 7) << 4;
#pragma unroll
  for (int dh = 0; dh < 2; ++dh) {
    const f32x16& ac = dh ? acc1 : acc0;
#pragma unroll
    for (int g3 = 0; g3 < 4; ++g3) {
      bf16x4 o4 = { (__bf16)(ac[4 * g3] * inv), (__bf16)(ac[4 * g3 + 1] * inv),
                    (__bf16)(ac[4 * g3 + 2] * inv), (__bf16)(ac[4 * g3 + 3] * inv) };
      *(bf16x4*)((char*)TR + qloc * 128 + ((dh * 64 + g3 * 16 + l5 * 8) ^ swq)) = o4;
    }
  }
  __syncthreads();

  const int b = bh >> 4, h = bh & 15;
  {
    int row = tid >> 1, half = tid & 1;
    int sw = (row & 7) << 4;
    unsigned short* gdst = ctx + (size_t)(b * 2048 + qbase + row) * 1024 + h * 64 + half * 32;
#pragma unroll
    for (int i = 0; i < 4; ++i) {
      bf16x8 vv = *(const bf16x8*)((const char*)TR + row * 128 + ((half * 64 + i * 16) ^ sw));
      *(bf16x8*)(gdst + i * 8) = vv;
    }
  }
#undef STAGE_KV
}

// ---------------- LayerNorm over D=1024 ----------------
__global__ void k_ln(const float* __restrict__ y, const float* __restrict__ gamma,
                     const float* __restrict__ beta, float* __restrict__ out) {
  const int row = blockIdx.x;
  const int tid = threadIdx.x;
  const float4 v = ((const float4*)(y + (size_t)row * 1024))[tid];
  float sum = v.x + v.y + v.z + v.w;
  float sq = v.x * v.x + v.y * v.y + v.z * v.z + v.w * v.w;
#pragma unroll
  for (int m = 1; m <= 32; m <<= 1) {
    sum += __shfl_xor(sum, m);
    sq  += __shfl_xor(sq, m);
  }
  __shared__ float s1[4], s2[4];
  const int wv = tid >> 6, lane = tid & 63;
  if (lane == 0) { s1[wv] = sum; s2[wv] = sq; }
  __syncthreads();
  sum = s1[0] + s1[1] + s1[2] + s1[3];
  sq  = s2[0] + s2[1] + s2[2] + s2[3];
  const float mu = sum * (1.f / 1024.f);
  const float rs = rsqrtf(sq * (1.f / 1024.f) - mu * mu + 1e-3f);
  const float4 g  = ((const float4*)gamma)[tid];
  const float4 bb = ((const float4*)beta)[tid];
  float4 o;
  o.x = (v.x - mu) * rs * g.x + bb.x;
  o.y = (v.y - mu) * rs * g.y + bb.y;
  o.z = (v.z - mu) * rs * g.z + bb.z;
  o.w = (v.w - mu) * rs * g.w + bb.w;
  ((float4*)(out + (size_t)row * 1024))[tid] = o;
}

extern "C" void kernel_launch(void* const* d_in, const int* in_sizes, int n_in,
                              void* d_out, int out_size, void* d_ws, size_t ws_size,
                              hipStream_t stream) {
  const float* x  = (const float*)d_in[0];
  const float* Wq = (const float*)d_in[1];
  const float* bq = (const float*)d_in[2];
  const float* Wk = (const float*)d_in[3];
  const float* bk = (const float*)d_in[4];
  const float* Wv = (const float*)d_in[5];
  const float* bv = (const float*)d_in[6];
  const float* Wo = (const float*)d_in[7];
  const float* bo = (const float*)d_in[8];
  const float* gamma = (const float*)d_in[9];
  const float* beta  = (const float*)d_in[10];
  float* out = (float*)d_out;

  char* ws = (char*)d_ws;
  const size_t MB = 1024 * 1024;
  unsigned short* xb  = (unsigned short*)(ws);            // 16MB  x bf16 [8192][1024]
  unsigned short* wqt = (unsigned short*)(ws + 16 * MB);  // 2MB   Wq^T bf16
  unsigned short* wkt = (unsigned short*)(ws + 18 * MB);
  unsigned short* wvt = (unsigned short*)(ws + 20 * MB);
  unsigned short* wot = (unsigned short*)(ws + 22 * MB);
  unsigned short* qb  = (unsigned short*)(ws + 24 * MB);  // 16MB  q [B,H,S,64]
  unsigned short* kb  = (unsigned short*)(ws + 40 * MB);  // 16MB  k [B,H,S,64]
  unsigned short* vtb = (unsigned short*)(ws + 56 * MB);  // 16MB  v^T [B,H,64,S]
  unsigned short* ctx = (unsigned short*)(ws + 72 * MB);  // 16MB  ctx [B,S,H,64]
  float* yb = (float*)(ws + 24 * MB);                     // 32MB  y fp32, aliases q/k

  k_convert<<<8192, 256, 0, stream>>>(x, xb, 2097152);
  dim3 tb(32, 8), tg(32, 32, 4);
  k_transpose4<<<tg, tb, 0, stream>>>(Wq, Wk, Wv, Wo, wqt, wkt, wvt, wot);

  // q = (x Wq + bq) * 0.125*log2(e)  (exp2-domain softmax); k = x Wk + bk
  k_gemm<0><<<dim3(64, 8), 256, 0, stream>>>(xb, wqt, bq, qb, nullptr, 1024, 0.18033688011112042f);
  k_gemm<0><<<dim3(64, 8), 256, 0, stream>>>(xb, wkt, bk, kb, nullptr, 1024, 1.0f);
  // v^T = Wv^T x^T  -> [B,H,64,S]
  k_gemm<1><<<dim3(8, 64), 256, 0, stream>>>(wvt, xb, bv, vtb, nullptr, 1024, 1.0f);

  k_attn<<<1024, 256, 0, stream>>>(qb, kb, vtb, ctx);

  // y = ctx Wo + bo + x  (fp32)
  k_gemm<2><<<dim3(64, 8), 256, 0, stream>>>(ctx, wot, bo, yb, x, 1024, 1.0f);

  k_ln<<<8192, 256, 0, stream>>>(yb, gamma, beta, out);
  (void)in_sizes; (void)n_in; (void)out_size; (void)ws_size;
}

// Round 6
// 206.645 us; speedup vs baseline: 1.5781x; 1.0065x over previous
//
#include <hip/hip_runtime.h>

typedef float f32x4 __attribute__((ext_vector_type(4)));
typedef float f32x16 __attribute__((ext_vector_type(16)));
typedef __bf16 bf16x8 __attribute__((ext_vector_type(8)));
typedef __bf16 bf16x4 __attribute__((ext_vector_type(4)));
typedef __bf16 bf16x2 __attribute__((ext_vector_type(2)));
typedef unsigned short us4 __attribute__((ext_vector_type(4)));

#define DEV __device__ __forceinline__

DEV unsigned short f2bf(float f) {
  union { float f; unsigned int u; } v; v.f = f;
  unsigned int u = v.u;
  return (unsigned short)((u + 0x7FFFu + ((u >> 16) & 1u)) >> 16);
}

typedef const __attribute__((address_space(1))) void* gvp;
typedef __attribute__((address_space(3))) void* lvp;

DEV void gll16(const void* g, void* l) {
  __builtin_amdgcn_global_load_lds((gvp)g, (lvp)l, 16, 0, 0);
}

DEV float fexp2(float x) { return __builtin_amdgcn_exp2f(x); }

// v_permlane32_swap_b32 a, b:  a' = {a_lo, b_lo}, b' = {a_hi, b_hi}
DEV void plswap(unsigned& a, unsigned& b) {
  asm("v_permlane32_swap_b32 %0, %1" : "+v"(a), "+v"(b));
}
DEV float xhalf_max(float v) {
  union { float f; unsigned u; } a, b;
  a.f = v; b.f = v;
  plswap(a.u, b.u);
  return fmaxf(a.f, b.f);
}
DEV float xhalf_sum(float v) {
  union { float f; unsigned u; } a, b;
  a.f = v; b.f = v;
  plswap(a.u, b.u);
  return a.f + b.f;
}

// ---------------- convert fp32 -> bf16 ----------------
__global__ void k_convert(const float* __restrict__ in, unsigned short* __restrict__ out, int n4) {
  int i = blockIdx.x * blockDim.x + threadIdx.x;
  if (i < n4) {
    float4 v = ((const float4*)in)[i];
    us4 o = { f2bf(v.x), f2bf(v.y), f2bf(v.z), f2bf(v.w) };
    ((us4*)out)[i] = o;
  }
}

// ---------------- transpose 4x 1024x1024 fp32 -> bf16 (z = which weight) ----------------
__global__ void k_transpose4(const float* __restrict__ w0, const float* __restrict__ w1,
                             const float* __restrict__ w2, const float* __restrict__ w3,
                             unsigned short* __restrict__ o0, unsigned short* __restrict__ o1,
                             unsigned short* __restrict__ o2, unsigned short* __restrict__ o3) {
  const float* in = (blockIdx.z == 0) ? w0 : (blockIdx.z == 1) ? w1 : (blockIdx.z == 2) ? w2 : w3;
  unsigned short* out = (blockIdx.z == 0) ? o0 : (blockIdx.z == 1) ? o1 : (blockIdx.z == 2) ? o2 : o3;
  __shared__ float tile[32][33];
  const int bx = blockIdx.x * 32, by = blockIdx.y * 32;
  const int tx = threadIdx.x, ty = threadIdx.y;
#pragma unroll
  for (int r = 0; r < 4; ++r)
    tile[ty + r * 8][tx] = in[(size_t)(by + ty + r * 8) * 1024 + bx + tx];
  __syncthreads();
#pragma unroll
  for (int r = 0; r < 4; ++r)
    out[(size_t)(bx + ty + r * 8) * 1024 + by + tx] = f2bf(tile[tx][ty + r * 8]);
}

// ---------------- fused QKV projection GEMM (z: 0=q, 1=k, 2=v^T) ----------------
__global__ void k_gemm_qkv(const unsigned short* __restrict__ xb,
                           const unsigned short* __restrict__ wqt,
                           const unsigned short* __restrict__ wkt,
                           const unsigned short* __restrict__ wvt,
                           const float* __restrict__ bq, const float* __restrict__ bk,
                           const float* __restrict__ bv,
                           unsigned short* __restrict__ qb, unsigned short* __restrict__ kb,
                           unsigned short* __restrict__ vtb) {
  __shared__ unsigned short As[128 * 64];
  __shared__ unsigned short Bs[128 * 64];
  const int tid = threadIdx.x;
  const int lane = tid & 63;
  const int wave = tid >> 6;
  const int l15 = lane & 15;
  const int lq  = lane >> 4;
  const int wm = wave >> 1, wn = wave & 1;
  const int z = blockIdx.z;

  const unsigned short* A;
  const unsigned short* Bt;
  int mbase, nbase;
  if (z == 2) { A = wvt; Bt = xb; mbase = blockIdx.y * 128; nbase = blockIdx.x * 128; }
  else        { A = xb; Bt = z ? wkt : wqt; mbase = blockIdx.x * 128; nbase = blockIdx.y * 128; }

  f32x4 acc[4][4] = {};

  for (int kt = 0; kt < 1024; kt += 64) {
    __syncthreads();
#pragma unroll
    for (int c = 0; c < 4; ++c) {
      int e = (c * 256 + tid) * 8;
      int row = e >> 6;
      int o2 = (e * 2) ^ ((row & 7) << 4);
      int col = (o2 >> 1) & 63;
      gll16(A + (size_t)(mbase + row) * 1024 + kt + col,
            As + (c * 256 + (tid & ~63)) * 8);
      gll16(Bt + (size_t)(nbase + row) * 1024 + kt + col,
            Bs + (c * 256 + (tid & ~63)) * 8);
    }
    __syncthreads();
#pragma unroll
    for (int ks = 0; ks < 2; ++ks) {
      bf16x8 af[4], bfv[4];
#pragma unroll
      for (int i = 0; i < 4; ++i) {
        int row = wm * 64 + i * 16 + l15;
        int off = row * 128 + ((((ks << 2) | lq) ^ (row & 7)) << 4);
        af[i] = *(const bf16x8*)((const char*)As + off);
      }
#pragma unroll
      for (int j = 0; j < 4; ++j) {
        int row = wn * 64 + j * 16 + l15;
        int off = row * 128 + ((((ks << 2) | lq) ^ (row & 7)) << 4);
        bfv[j] = *(const bf16x8*)((const char*)Bs + off);
      }
#pragma unroll
      for (int i = 0; i < 4; ++i)
#pragma unroll
        for (int j = 0; j < 4; ++j)
          acc[i][j] = __builtin_amdgcn_mfma_f32_16x16x32_bf16(af[i], bfv[j], acc[i][j], 0, 0, 0);
    }
  }

  const float scale = (z == 0) ? 0.18033688011112042f : 1.0f;
  const float* bias = (z == 0) ? bq : (z == 1) ? bk : bv;
  unsigned short* outp = (z == 0) ? qb : (z == 1) ? kb : vtb;

#pragma unroll
  for (int i = 0; i < 4; ++i) {
#pragma unroll
    for (int j = 0; j < 4; ++j) {
#pragma unroll
      for (int r = 0; r < 4; ++r) {
        int mi = mbase + wm * 64 + i * 16 + lq * 4 + r;
        int nj = nbase + wn * 64 + j * 16 + l15;
        float v = acc[i][j][r];
        if (z < 2) {
          v = (v + bias[nj]) * scale;
          int b = mi >> 11, s = mi & 2047, h = nj >> 6, kk = nj & 63;
          outp[(((size_t)((b << 4) + h) * 2048 + s) << 6) + kk] = f2bf(v);
        } else {
          v = v + bias[mi];
          int h = mi >> 6, d = mi & 63, b = nj >> 11, s = nj & 2047;
          outp[(((size_t)((b << 4) + h) << 6) + d) * 2048 + s] = f2bf(v);
        }
      }
    }
  }
}

// ---------------- output-projection GEMM: y = ctx*Wo + bo + x (fp32) ----------------
__global__ void k_gemm_out(const unsigned short* __restrict__ A,
                           const unsigned short* __restrict__ Bt,
                           const float* __restrict__ bias,
                           float* __restrict__ outp,
                           const float* __restrict__ xres) {
  __shared__ unsigned short As[128 * 64];
  __shared__ unsigned short Bs[128 * 64];
  const int tid = threadIdx.x;
  const int lane = tid & 63;
  const int wave = tid >> 6;
  const int l15 = lane & 15;
  const int lq  = lane >> 4;
  const int wm = wave >> 1, wn = wave & 1;
  const int mbase = blockIdx.x * 128;
  const int nbase = blockIdx.y * 128;

  f32x4 acc[4][4] = {};

  for (int kt = 0; kt < 1024; kt += 64) {
    __syncthreads();
#pragma unroll
    for (int c = 0; c < 4; ++c) {
      int e = (c * 256 + tid) * 8;
      int row = e >> 6;
      int o2 = (e * 2) ^ ((row & 7) << 4);
      int col = (o2 >> 1) & 63;
      gll16(A + (size_t)(mbase + row) * 1024 + kt + col,
            As + (c * 256 + (tid & ~63)) * 8);
      gll16(Bt + (size_t)(nbase + row) * 1024 + kt + col,
            Bs + (c * 256 + (tid & ~63)) * 8);
    }
    __syncthreads();
#pragma unroll
    for (int ks = 0; ks < 2; ++ks) {
      bf16x8 af[4], bfv[4];
#pragma unroll
      for (int i = 0; i < 4; ++i) {
        int row = wm * 64 + i * 16 + l15;
        int off = row * 128 + ((((ks << 2) | lq) ^ (row & 7)) << 4);
        af[i] = *(const bf16x8*)((const char*)As + off);
      }
#pragma unroll
      for (int j = 0; j < 4; ++j) {
        int row = wn * 64 + j * 16 + l15;
        int off = row * 128 + ((((ks << 2) | lq) ^ (row & 7)) << 4);
        bfv[j] = *(const bf16x8*)((const char*)Bs + off);
      }
#pragma unroll
      for (int i = 0; i < 4; ++i)
#pragma unroll
        for (int j = 0; j < 4; ++j)
          acc[i][j] = __builtin_amdgcn_mfma_f32_16x16x32_bf16(af[i], bfv[j], acc[i][j], 0, 0, 0);
    }
  }

#pragma unroll
  for (int i = 0; i < 4; ++i)
#pragma unroll
    for (int j = 0; j < 4; ++j)
#pragma unroll
      for (int r = 0; r < 4; ++r) {
        int mi = mbase + wm * 64 + i * 16 + lq * 4 + r;
        int nj = nbase + wn * 64 + j * 16 + l15;
        size_t idx = (size_t)mi * 1024 + nj;
        outp[idx] = acc[i][j][r] + bias[nj] + xres[idx];
      }
}

// ---------------- flash attention v6: 64 q/wave, P in regs, permlane exchange ----------------
// q,k: [B,H,S,64] bf16 (q pre-scaled by 0.125*log2e); vt: [B,H,64,S] bf16
// ctx out: [B,S,H,64] bf16.  QBLK=256, 4 waves x 2 q-groups of 32, KVBLK=64.
__global__ __launch_bounds__(256, 2) void k_attn(const unsigned short* __restrict__ q,
                       const unsigned short* __restrict__ k,
                       const unsigned short* __restrict__ vt,
                       unsigned short* __restrict__ ctx) {
  __shared__ unsigned short KV[2][2][64 * 64];   // [buf][K|V^T] 32 KB

  const int tid = threadIdx.x;
  const int lane = tid & 63;
  const int wave = tid >> 6;
  const int l31 = lane & 31;
  const int l5 = lane >> 5;

  // 512 blocks: 64 per XCD = 8 full heads
  const int bid = blockIdx.x;
  const int swz = (bid & 7) * 64 + (bid >> 3);
  const int bh = swz >> 3;
  const int qtile = swz & 7;
  const int qbase = qtile * 256;
  const size_t sl = (size_t)bh << 17;

  // ---- Q direct to registers, 2 q-groups
  bf16x8 qrA[4], qrB[4];
  {
    const int qrowA = qbase + wave * 64 + l31;
    const int qrowB = qrowA + 32;
#pragma unroll
    for (int ds = 0; ds < 4; ++ds) {
      qrA[ds] = *(const bf16x8*)(q + sl + (size_t)qrowA * 64 + ds * 16 + l5 * 8);
      qrB[ds] = *(const bf16x8*)(q + sl + (size_t)qrowB * 64 + ds * 16 + l5 * 8);
    }
  }

#define STAGE_KV(BUF, TT) do {                                                 \
    const int kvb_ = (TT) * 64;                                                \
    _Pragma("unroll")                                                          \
    for (int c = 0; c < 2; ++c) {                                              \
      int e = (c * 256 + tid) * 8;                                             \
      int row_ = e >> 6;                                                       \
      int o2 = (e * 2) ^ ((row_ & 7) << 4);                                    \
      int col_ = (o2 >> 1) & 63;                                               \
      gll16(k + sl + (size_t)(kvb_ + row_) * 64 + col_,                        \
            KV[BUF][0] + (c * 256 + (tid & ~63)) * 8);                         \
      gll16(vt + sl + (size_t)row_ * 2048 + kvb_ + col_,                       \
            KV[BUF][1] + (c * 256 + (tid & ~63)) * 8);                         \
    }                                                                          \
  } while (0)

  STAGE_KV(0, 0);
  __syncthreads();

  f32x16 accA0 = {}, accA1 = {}, accB0 = {}, accB1 = {};
  float mrA = -1e30f, lrA = 0.f, mrB = -1e30f, lrB = 0.f;
  unsigned pkA0[8], pkA1[8], pkB0[8], pkB1[8];

// QK^T (both kv-halves) + online softmax for one q-group
#define QK_SOFTMAX(QR, A0, A1, MR, LR, P0, P1) do {                            \
    f32x16 s0 = {}, s1 = {};                                                   \
    __builtin_amdgcn_s_setprio(1);                                             \
    _Pragma("unroll") for (int ds = 0; ds < 4; ++ds)                           \
      s0 = __builtin_amdgcn_mfma_f32_32x32x16_bf16(kf0[ds], QR[ds], s0, 0,0,0);\
    _Pragma("unroll") for (int ds = 0; ds < 4; ++ds)                           \
      s1 = __builtin_amdgcn_mfma_f32_32x32x16_bf16(kf1[ds], QR[ds], s1, 0,0,0);\
    __builtin_amdgcn_s_setprio(0);                                             \
    float tmax[8];                                                             \
    _Pragma("unroll") for (int i = 0; i < 8; ++i)                              \
      tmax[i] = fmaxf(s0[i], s0[i + 8]);                                       \
    _Pragma("unroll") for (int i = 0; i < 8; ++i)                              \
      tmax[i] = fmaxf(tmax[i], fmaxf(s1[i], s1[i + 8]));                       \
    float tm = fmaxf(fmaxf(fmaxf(tmax[0], tmax[1]), fmaxf(tmax[2], tmax[3])),  \
                     fmaxf(fmaxf(tmax[4], tmax[5]), fmaxf(tmax[6], tmax[7]))); \
    tm = xhalf_max(tm);                                                        \
    if (!__all(tm <= MR + 10.0f)) {                                            \
      float mnew = fmaxf(MR, tm);                                              \
      float alpha = fexp2(MR - mnew);                                          \
      A0 *= alpha; A1 *= alpha; LR *= alpha; MR = mnew;                        \
    }                                                                          \
    const float mc_ = MR;                                                      \
    float r0 = 0.f, r1 = 0.f, r2 = 0.f, r3 = 0.f;                              \
    _Pragma("unroll") for (int m = 0; m < 8; ++m) {                            \
      float a0 = fexp2(s0[2*m] - mc_), a1 = fexp2(s0[2*m+1] - mc_);            \
      float b0 = fexp2(s1[2*m] - mc_), b1 = fexp2(s1[2*m+1] - mc_);            \
      r0 += a0; r1 += a1; r2 += b0; r3 += b1;                                  \
      union { bf16x2 v; unsigned u; } ua, ub;                                  \
      ua.v = bf16x2{ (__bf16)a0, (__bf16)a1 };                                 \
      ub.v = bf16x2{ (__bf16)b0, (__bf16)b1 };                                 \
      P0[m] = ua.u; P1[m] = ub.u;                                              \
    }                                                                          \
    LR += (r0 + r1) + (r2 + r3);                                               \
  } while (0)

// PV for one q-group: permlane exchange + 8 mfma
#define PV_STEP(P0, P1, A0, A1) do {                                           \
    _Pragma("unroll") for (int kvh = 0; kvh < 2; ++kvh) {                      \
      unsigned* pk_ = kvh ? (P1) : (P0);                                       \
      _Pragma("unroll") for (int g = 0; g < 2; ++g) {                          \
        unsigned a0_ = pk_[4*g],     b0_ = pk_[4*g + 2];                       \
        unsigned a1_ = pk_[4*g + 1], b1_ = pk_[4*g + 3];                       \
        plswap(a0_, b0_);                                                      \
        plswap(a1_, b1_);                                                      \
        union { unsigned u[4]; bf16x8 v; } pf;                                 \
        pf.u[0] = a0_; pf.u[1] = a1_; pf.u[2] = b0_; pf.u[3] = b1_;            \
        const int kvg = 2 * kvh + g;                                           \
        __builtin_amdgcn_s_setprio(1);                                         \
        A0 = __builtin_amdgcn_mfma_f32_32x32x16_bf16(av0[kvg], pf.v, A0, 0,0,0);\
        A1 = __builtin_amdgcn_mfma_f32_32x32x16_bf16(av1[kvg], pf.v, A1, 0,0,0);\
        __builtin_amdgcn_s_setprio(0);                                         \
      }                                                                        \
    }                                                                          \
  } while (0)

  for (int t = 0; t < 32; ++t) {
    const int cur = t & 1;
    if (t < 31) STAGE_KV(cur ^ 1, t + 1);

    const char* Ksc = (const char*)KV[cur][0];
    const char* Vtc = (const char*)KV[cur][1];

    // K fragments, both kv-halves (shared by both q-groups)
    bf16x8 kf0[4], kf1[4];
#pragma unroll
    for (int ds = 0; ds < 4; ++ds) {
      int r0 = l31, r1 = 32 + l31;
      kf0[ds] = *(const bf16x8*)(Ksc + r0 * 128 + ((ds * 32 + l5 * 16) ^ ((r0 & 7) << 4)));
      kf1[ds] = *(const bf16x8*)(Ksc + r1 * 128 + ((ds * 32 + l5 * 16) ^ ((r1 & 7) << 4)));
    }

    QK_SOFTMAX(qrA, accA0, accA1, mrA, lrA, pkA0, pkA1);
    QK_SOFTMAX(qrB, accB0, accB1, mrB, lrB, pkB0, pkB1);

    // V^T fragments (shared by both q-groups)
    bf16x8 av0[4], av1[4];
#pragma unroll
    for (int kvg = 0; kvg < 4; ++kvg) {
      int r0 = l31, r1 = 32 + l31;
      av0[kvg] = *(const bf16x8*)(Vtc + r0 * 128 + ((kvg * 32 + l5 * 16) ^ ((r0 & 7) << 4)));
      av1[kvg] = *(const bf16x8*)(Vtc + r1 * 128 + ((kvg * 32 + l5 * 16) ^ ((r1 & 7) << 4)));
    }

    PV_STEP(pkA0, pkA1, accA0, accA1);
    PV_STEP(pkB0, pkB1, accB0, accB1);

    __syncthreads();
  }

  // ---- epilogue: normalize (lane-local), transpose via LDS, coalesced store
  const float invA = 1.f / xhalf_sum(lrA);
  const float invB = 1.f / xhalf_sum(lrB);

  unsigned short* TR = (unsigned short*)KV;   // 32 KB scratch: [256 q][64 d]
#define WRITE_O(ACC0, ACC1, INV, QG) do {                                      \
    const int qloc = wave * 64 + (QG) * 32 + l31;                              \
    const int swq = (qloc & 7) << 4;                                           \
    _Pragma("unroll") for (int dh = 0; dh < 2; ++dh) {                         \
      const f32x16& ac = dh ? (ACC1) : (ACC0);                                 \
      _Pragma("unroll") for (int g3 = 0; g3 < 4; ++g3) {                       \
        bf16x4 o4 = { (__bf16)(ac[4*g3] * (INV)),  (__bf16)(ac[4*g3+1] * (INV)), \
                      (__bf16)(ac[4*g3+2] * (INV)),(__bf16)(ac[4*g3+3] * (INV)) }; \
        *(bf16x4*)((char*)TR + qloc * 128 + ((dh * 64 + g3 * 16 + l5 * 8) ^ swq)) = o4; \
      }                                                                        \
    }                                                                          \
  } while (0)

  WRITE_O(accA0, accA1, invA, 0);
  WRITE_O(accB0, accB1, invB, 1);
  __syncthreads();

  const int b = bh >> 4, h = bh & 15;
#pragma unroll
  for (int pass = 0; pass < 2; ++pass) {
    int row = pass * 128 + (tid >> 1), half = tid & 1;
    int sw = (row & 7) << 4;
    unsigned short* gdst = ctx + (size_t)(b * 2048 + qbase + row) * 1024 + h * 64 + half * 32;
#pragma unroll
    for (int i = 0; i < 4; ++i) {
      bf16x8 vv = *(const bf16x8*)((const char*)TR + row * 128 + ((half * 64 + i * 16) ^ sw));
      *(bf16x8*)(gdst + i * 8) = vv;
    }
  }
#undef STAGE_KV
#undef QK_SOFTMAX
#undef PV_STEP
#undef WRITE_O
}

// ---------------- LayerNorm over D=1024 ----------------
__global__ void k_ln(const float* __restrict__ y, const float* __restrict__ gamma,
                     const float* __restrict__ beta, float* __restrict__ out) {
  const int row = blockIdx.x;
  const int tid = threadIdx.x;
  const float4 v = ((const float4*)(y + (size_t)row * 1024))[tid];
  float sum = v.x + v.y + v.z + v.w;
  float sq = v.x * v.x + v.y * v.y + v.z * v.z + v.w * v.w;
#pragma unroll
  for (int m = 1; m <= 32; m <<= 1) {
    sum += __shfl_xor(sum, m);
    sq  += __shfl_xor(sq, m);
  }
  __shared__ float s1[4], s2[4];
  const int wv = tid >> 6, lane = tid & 63;
  if (lane == 0) { s1[wv] = sum; s2[wv] = sq; }
  __syncthreads();
  sum = s1[0] + s1[1] + s1[2] + s1[3];
  sq  = s2[0] + s2[1] + s2[2] + s2[3];
  const float mu = sum * (1.f / 1024.f);
  const float rs = rsqrtf(sq * (1.f / 1024.f) - mu * mu + 1e-3f);
  const float4 g  = ((const float4*)gamma)[tid];
  const float4 bb = ((const float4*)beta)[tid];
  float4 o;
  o.x = (v.x - mu) * rs * g.x + bb.x;
  o.y = (v.y - mu) * rs * g.y + bb.y;
  o.z = (v.z - mu) * rs * g.z + bb.z;
  o.w = (v.w - mu) * rs * g.w + bb.w;
  ((float4*)(out + (size_t)row * 1024))[tid] = o;
}

extern "C" void kernel_launch(void* const* d_in, const int* in_sizes, int n_in,
                              void* d_out, int out_size, void* d_ws, size_t ws_size,
                              hipStream_t stream) {
  const float* x  = (const float*)d_in[0];
  const float* Wq = (const float*)d_in[1];
  const float* bq = (const float*)d_in[2];
  const float* Wk = (const float*)d_in[3];
  const float* bk = (const float*)d_in[4];
  const float* Wv = (const float*)d_in[5];
  const float* bv = (const float*)d_in[6];
  const float* Wo = (const float*)d_in[7];
  const float* bo = (const float*)d_in[8];
  const float* gamma = (const float*)d_in[9];
  const float* beta  = (const float*)d_in[10];
  float* out = (float*)d_out;

  char* ws = (char*)d_ws;
  const size_t MB = 1024 * 1024;
  unsigned short* xb  = (unsigned short*)(ws);            // 16MB  x bf16 [8192][1024]
  unsigned short* wqt = (unsigned short*)(ws + 16 * MB);  // 2MB   Wq^T bf16
  unsigned short* wkt = (unsigned short*)(ws + 18 * MB);
  unsigned short* wvt = (unsigned short*)(ws + 20 * MB);
  unsigned short* wot = (unsigned short*)(ws + 22 * MB);
  unsigned short* qb  = (unsigned short*)(ws + 24 * MB);  // 16MB  q [B,H,S,64]
  unsigned short* kb  = (unsigned short*)(ws + 40 * MB);  // 16MB  k [B,H,S,64]
  unsigned short* vtb = (unsigned short*)(ws + 56 * MB);  // 16MB  v^T [B,H,64,S]
  unsigned short* ctx = (unsigned short*)(ws + 72 * MB);  // 16MB  ctx [B,S,H,64]
  float* yb = (float*)(ws + 24 * MB);                     // 32MB  y fp32, aliases q/k

  k_convert<<<8192, 256, 0, stream>>>(x, xb, 2097152);
  dim3 tb(32, 8), tg(32, 32, 4);
  k_transpose4<<<tg, tb, 0, stream>>>(Wq, Wk, Wv, Wo, wqt, wkt, wvt, wot);

  // q = (x Wq + bq)*0.125*log2e ; k = x Wk + bk ; v^T = Wv^T x^T — one launch
  k_gemm_qkv<<<dim3(64, 8, 3), 256, 0, stream>>>(xb, wqt, wkt, wvt, bq, bk, bv, qb, kb, vtb);

  k_attn<<<512, 256, 0, stream>>>(qb, kb, vtb, ctx);

  // y = ctx Wo + bo + x  (fp32)
  k_gemm_out<<<dim3(64, 8), 256, 0, stream>>>(ctx, wot, bo, yb, x);

  k_ln<<<8192, 256, 0, stream>>>(yb, gamma, beta, out);
  (void)in_sizes; (void)n_in; (void)out_size; (void)ws_size;
}